// Round 3
// baseline (2377.058 us; speedup 1.0000x reference)
//
#include <hip/hip_runtime.h>
#include <math.h>

#define NA 10000
#define FD 128
#define KR 64
#define DEGC 32
#define NE (NA*DEGC)
#define NOUTS_C 2005
#define NOUT_FINAL 2001

typedef __attribute__((ext_vector_type(8))) short bh8;
typedef __attribute__((ext_vector_type(4))) float fx4;

__device__ __forceinline__ float sspf(float x){
    return fmaxf(x, 0.0f) + log1pf(expf(-fabsf(x))) - 0.6931471805599453f;
}
__device__ __forceinline__ unsigned short f2bf(float x){
    unsigned int u = __float_as_uint(x);
    unsigned int r = (u + 0x7fffu + ((u >> 16) & 1u)) >> 16;
    return (unsigned short)r;
}
__device__ __forceinline__ fx4 mfma16(bh8 a, bh8 b, fx4 c){
    return __builtin_amdgcn_mfma_f32_16x16x32_bf16(a, b, c, 0, 0, 0);
}
__device__ __forceinline__ void gll16(const void* g, void* l){
    __builtin_amdgcn_global_load_lds(
        (const __attribute__((address_space(1))) unsigned int*)g,
        (__attribute__((address_space(3))) unsigned int*)l, 16, 0, 0);
}

// ---------------- edge geometry ----------------
__global__ void k_dij(const float* __restrict__ R, const int* __restrict__ idx_i,
                      const int* __restrict__ idx_j, float* __restrict__ dij_out){
    int e = blockIdx.x*256 + threadIdx.x;
    if (e >= NE) return;
    int i = idx_i[e], j = idx_j[e];
    float dx = R[i*3+0] - R[j*3+0];
    float dy = R[i*3+1] - R[j*3+1];
    float dz = R[i*3+2] - R[j*3+2];
    dij_out[e] = sqrtf(fmaxf(dx*dx + dy*dy + dz*dz, 0.0f));
}

// rbf written as bf16 swizzled LDS-image rows [e][64k]
__global__ void k_rbf_bf(const float* __restrict__ dij_in, short* __restrict__ rbf_bf,
                         float gamma, float mu0, float dmu){
    int gid = blockIdx.x*256 + threadIdx.x;   // NE*32
    int e = gid >> 5, kp = (gid & 31)*2;
    float d = dij_in[e];
    float t = d * 0.1f;
    float cut = 0.0f;
    if (d < 10.0f){
        float t2 = t*t, t3 = t2*t, t4 = t2*t2, t5 = t4*t;
        cut = 1.0f - 6.0f*t5 + 15.0f*t4 - 10.0f*t3;
    }
    float ed = expf(-d);
    float u0 = ed - (mu0 + (float)kp*dmu);
    float u1 = ed - (mu0 + (float)(kp+1)*dmu);
    float v0 = cut * expf(-gamma*u0*u0);
    float v1 = cut * expf(-gamma*u1*u1);
    unsigned int pk = (unsigned int)f2bf(v0) | ((unsigned int)f2bf(v1) << 16);
    int idx = e*64 + (((kp>>3) ^ (e&7))*8) + (kp&7);
    *(unsigned int*)&rbf_bf[idx] = pk;
}

// ---------------- init ----------------
__global__ void k_init(const float* __restrict__ QaAin, const float* __restrict__ QaBin,
                       const int* __restrict__ mol, float* __restrict__ QaA,
                       float* __restrict__ QaB, float* __restrict__ QAmol,
                       float* __restrict__ QBmol){
    int a = blockIdx.x*256 + threadIdx.x;
    if (a >= NA) return;
    float qa = QaAin[a], qb = QaBin[a];
    QaA[a] = qa; QaB[a] = qb;
    int m = mol[a];
    atomicAdd(&QAmol[m], qa);
    atomicAdd(&QBmol[m], qb);
}

// ---------------- weight conversion ----------------
__global__ void k_cvtW(const float* __restrict__ em_W1, const float* __restrict__ em_W2,
                       const float* __restrict__ iWi, const float* __restrict__ iWj,
                       const float* __restrict__ iWout, const float* __restrict__ irW1,
                       const float* __restrict__ irW2, const float* __restrict__ arW1,
                       const float* __restrict__ arW2, const float* __restrict__ orW1,
                       const float* __restrict__ orW2, short* __restrict__ img){
    int gid = blockIdx.x*256 + threadIdx.x;   // 41*2048
    if (gid >= 41*2048) return;
    int m = gid >> 11;
    int loc = gid & 2047;
    int n = loc >> 4, s = loc & 15;
    const float* src; int mm;
    if      (m < 1){ src = em_W1; mm = m; }
    else if (m < 2){ src = em_W2; mm = m-1; }
    else if (m < 5){ src = iWi;   mm = m-2; }
    else if (m < 8){ src = iWj;   mm = m-5; }
    else if (m < 11){ src = iWout; mm = m-8; }
    else if (m < 17){ src = irW1;  mm = m-11; }
    else if (m < 23){ src = irW2;  mm = m-17; }
    else if (m < 29){ src = arW1;  mm = m-23; }
    else if (m < 35){ src = arW2;  mm = m-29; }
    else if (m < 38){ src = orW1;  mm = m-35; }
    else            { src = orW2;  mm = m-38; }
    src += (size_t)mm * 16384;
    int kbase = (s ^ (n&7)) * 8;
    bh8 pk;
    #pragma unroll
    for (int j = 0; j < 8; ++j) pk[j] = (short)f2bf(src[(kbase+j)*128 + n]);
    *(bh8*)&img[m*16384 + n*128 + s*8] = pk;
}

// biases + iu gathered into one image matching wmat indices
__global__ void k_cvtB(const float* __restrict__ em_b1, const float* __restrict__ em_b2,
                       const float* __restrict__ ibi, const float* __restrict__ ibj,
                       const float* __restrict__ ibout, const float* __restrict__ irb1,
                       const float* __restrict__ irb2, const float* __restrict__ arb1,
                       const float* __restrict__ arb2, const float* __restrict__ orb1,
                       const float* __restrict__ orb2, const float* __restrict__ iu,
                       float* __restrict__ bimg){
    int gid = blockIdx.x*256 + threadIdx.x;  // 44*128
    if (gid >= 44*128) return;
    int m = gid >> 7, c = gid & 127;
    float v;
    if      (m < 1)  v = em_b1[c];
    else if (m < 2)  v = em_b2[c];
    else if (m < 5)  v = ibi[(m-2)*128+c];
    else if (m < 8)  v = ibj[(m-5)*128+c];
    else if (m < 11) v = ibout[(m-8)*128+c];
    else if (m < 17) v = irb1[(m-11)*128+c];
    else if (m < 23) v = irb2[(m-17)*128+c];
    else if (m < 29) v = arb1[(m-23)*128+c];
    else if (m < 35) v = arb2[(m-29)*128+c];
    else if (m < 38) v = orb1[(m-35)*128+c];
    else if (m < 41) v = orb2[(m-38)*128+c];
    else             v = iu[(m-41)*128+c];
    bimg[gid] = v;
}

// iWrbf [3][64][128] -> image
__global__ void k_cvt_wrbf(const float* __restrict__ iWrbf, short* __restrict__ img){
    int gid = blockIdx.x*256 + threadIdx.x;   // 3*1024
    if (gid >= 3*1024) return;
    int i = gid >> 10;
    int loc = gid & 1023;
    int n = loc >> 3, s = loc & 7;
    const float* src = iWrbf + (size_t)i*8192;
    int kbase = (s ^ (n&7)) * 8;
    bh8 pk;
    #pragma unroll
    for (int j = 0; j < 8; ++j) pk[j] = (short)f2bf(src[(kbase+j)*128 + n]);
    *(bh8*)&img[i*8192 + n*64 + s*8] = pk;
}

// oW [3][128][2005] -> image[kk][n][32k]
__global__ void k_cvt_oW(const float* __restrict__ oW, short* __restrict__ img){
    int gid = blockIdx.x*256 + threadIdx.x;   // 12*2048*4
    if (gid >= 12*2048*4) return;
    int kk = gid >> 13;
    int loc = gid & 8191;
    int n = loc >> 2, s = loc & 3;
    int seg = kk >> 2;
    int kbase = (s ^ (n&3)) * 8;
    bh8 pk;
    #pragma unroll
    for (int j = 0; j < 8; ++j){
        int kseg = (kk&3)*32 + kbase + j;
        float v = (n < NOUTS_C) ? oW[((size_t)seg*128 + kseg)*NOUTS_C + n] : 0.0f;
        pk[j] = (short)f2bf(v);
    }
    *(bh8*)&img[((size_t)kk*2048 + n)*32 + s*8] = pk;
}

// ================= chain-kernel helpers (BM=32, 4 waves) =================
__device__ __forceinline__ void gemm32f(const short* Ab, const short* __restrict__ W,
                                        int g, int l15, int c0, int c1, fx4 acc[2][2]){
    #pragma unroll
    for (int kk = 0; kk < 4; ++kk){
        int q = kk*4 + g;
        bh8 a0 = *(const bh8*)&Ab[l15*128 + ((q ^ (l15&7))*8)];
        bh8 a1 = *(const bh8*)&Ab[(16+l15)*128 + ((q ^ (l15&7))*8)];
        bh8 b0 = *(const bh8*)&W[c0*128 + ((q ^ (c0&7))*8)];
        bh8 b1 = *(const bh8*)&W[c1*128 + ((q ^ (c1&7))*8)];
        acc[0][0] = mfma16(a0, b0, acc[0][0]);
        acc[0][1] = mfma16(a0, b1, acc[0][1]);
        acc[1][0] = mfma16(a1, b0, acc[1][0]);
        acc[1][1] = mfma16(a1, b1, acc[1][1]);
    }
}
#define ZACC { acc[0][0]=(fx4){0,0,0,0}; acc[0][1]=(fx4){0,0,0,0}; \
               acc[1][0]=(fx4){0,0,0,0}; acc[1][1]=(fx4){0,0,0,0}; }

__device__ __forceinline__ void epi_ts(short* dst, fx4 acc[2][2], const float* b,
                                       int g, int l15, int c0, int c1){
    float b0 = b[c0], b1 = b[c1];
    #pragma unroll
    for (int rt = 0; rt < 2; ++rt)
    #pragma unroll
    for (int r = 0; r < 4; ++r){
        int row = rt*16 + g*4 + r;
        dst[row*128 + (((c0>>3) ^ (row&7))*8) + (c0&7)] = (short)f2bf(sspf(acc[rt][0][r] + b0));
        dst[row*128 + (((c1>>3) ^ (row&7))*8) + (c1&7)] = (short)f2bf(sspf(acc[rt][1][r] + b1));
    }
}
__device__ __forceinline__ void epi_xadd(float xr[2][2][4], fx4 acc[2][2], const float* b,
                                         int c0, int c1){
    float b0 = b[c0], b1 = b[c1];
    #pragma unroll
    for (int rt = 0; rt < 2; ++rt)
    #pragma unroll
    for (int r = 0; r < 4; ++r){
        xr[rt][0][r] += acc[rt][0][r] + b0;
        xr[rt][1][r] += acc[rt][1][r] + b1;
    }
}
__device__ __forceinline__ void write_xr(short* dst, float xr[2][2][4],
                                         int g, int l15, int c0, int c1){
    #pragma unroll
    for (int rt = 0; rt < 2; ++rt)
    #pragma unroll
    for (int r = 0; r < 4; ++r){
        int row = rt*16 + g*4 + r;
        dst[row*128 + (((c0>>3) ^ (row&7))*8) + (c0&7)] = (short)f2bf(sspf(xr[rt][0][r]));
        dst[row*128 + (((c1>>3) ^ (row&7))*8) + (c1&7)] = (short)f2bf(sspf(xr[rt][1][r]));
    }
}
__device__ __forceinline__ void store_xr(float* dst, float xr[2][2][4], int r0,
                                         int g, int l15, int c0, int c1){
    #pragma unroll
    for (int rt = 0; rt < 2; ++rt)
    #pragma unroll
    for (int r = 0; r < 4; ++r){
        int row = r0 + rt*16 + g*4 + r;
        if (row < NA){
            dst[(size_t)row*FD + c0] = xr[rt][0][r];
            dst[(size_t)row*FD + c1] = xr[rt][1][r];
        }
    }
}
__device__ __forceinline__ void store_ssp(float* dst, fx4 acc[2][2], const float* b, int r0,
                                          int g, int l15, int c0, int c1){
    float b0 = b[c0], b1 = b[c1];
    #pragma unroll
    for (int rt = 0; rt < 2; ++rt)
    #pragma unroll
    for (int r = 0; r < 4; ++r){
        int row = r0 + rt*16 + g*4 + r;
        if (row < NA){
            dst[(size_t)row*FD + c0] = sspf(acc[rt][0][r] + b0);
            dst[(size_t)row*FD + c1] = sspf(acc[rt][1][r] + b1);
        }
    }
}
__device__ __forceinline__ void stage_A32(short* As, const float* src, int r0, int tid, bool dossp){
    int row = tid >> 3, cb = tid & 7;
    const float* p = src + (size_t)(r0+row)*FD + cb*16;
    float v[16];
    *(float4*)&v[0]  = *(const float4*)p;
    *(float4*)&v[4]  = *(const float4*)(p+4);
    *(float4*)&v[8]  = *(const float4*)(p+8);
    *(float4*)&v[12] = *(const float4*)(p+12);
    if (dossp){
        #pragma unroll
        for (int t = 0; t < 16; ++t) v[t] = sspf(v[t]);
    }
    bh8 p0, p1;
    #pragma unroll
    for (int t = 0; t < 8; ++t){ p0[t] = (short)f2bf(v[t]); p1[t] = (short)f2bf(v[8+t]); }
    int s0 = cb*2, s1 = s0+1;
    *(bh8*)&As[row*128 + ((s0 ^ (row&7))*8)] = p0;
    *(bh8*)&As[row*128 + ((s1 ^ (row&7))*8)] = p1;
}

// ---------------- pre: embedding chain + dual(i=0) ----------------
__global__ __launch_bounds__(256) void k_pre(
    const short* __restrict__ wmat, const float* __restrict__ bimg,
    const int* __restrict__ Z, const float* __restrict__ M,
    const float* __restrict__ QaA, const float* __restrict__ QaB,
    const float* __restrict__ em_W0, const float* __restrict__ em_b0,
    float* __restrict__ x, float* __restrict__ xi, float* __restrict__ xj)
{
    __shared__ __align__(16) short As[4096];
    __shared__ __align__(16) short Ts[4096];
    __shared__ float fs[32][4];
    const int tid = threadIdx.x, wv = tid>>6, ln = tid&63, g = ln>>4, l15 = ln&15;
    const int r0 = blockIdx.x*32;
    const int c0 = wv*32 + l15, c1 = c0 + 16;
    if (tid < 128){
        int rr = tid>>2, k = tid&3;
        int a = min(r0+rr, NA-1);
        fs[rr][k] = (k==0) ? (float)Z[a] : (k==1) ? M[a] : (k==2) ? QaA[a] : QaB[a];
    }
    __syncthreads();
    {   // h1 = ssp(f @ em_W0 + b0) -> As
        int row = tid>>3, cb = tid&7;
        float v[16];
        #pragma unroll
        for (int t = 0; t < 16; ++t){
            int c = cb*16 + t;
            v[t] = sspf(em_b0[c] + fs[row][0]*em_W0[c] + fs[row][1]*em_W0[128+c]
                        + fs[row][2]*em_W0[256+c] + fs[row][3]*em_W0[384+c]);
        }
        bh8 p0, p1;
        #pragma unroll
        for (int t = 0; t < 8; ++t){ p0[t] = (short)f2bf(v[t]); p1[t] = (short)f2bf(v[8+t]); }
        int s0 = cb*2, s1 = s0+1;
        *(bh8*)&As[row*128 + ((s0 ^ (row&7))*8)] = p0;
        *(bh8*)&As[row*128 + ((s1 ^ (row&7))*8)] = p1;
    }
    __syncthreads();
    fx4 acc[2][2];
    float xr[2][2][4];
    // P1: em_W1
    ZACC; gemm32f(As, wmat + 0*16384, g, l15, c0, c1, acc);
    epi_ts(Ts, acc, bimg + 0*128, g, l15, c0, c1);
    __syncthreads();
    // P2: em_W2 -> x (no ssp, no add)
    ZACC; gemm32f(Ts, wmat + 1*16384, g, l15, c0, c1, acc);
    {
        const float* b = bimg + 1*128;
        float b0 = b[c0], b1 = b[c1];
        #pragma unroll
        for (int rt = 0; rt < 2; ++rt)
        #pragma unroll
        for (int r = 0; r < 4; ++r){
            xr[rt][0][r] = acc[rt][0][r] + b0;
            xr[rt][1][r] = acc[rt][1][r] + b1;
        }
    }
    store_xr(x, xr, r0, g, l15, c0, c1);
    write_xr(As, xr, g, l15, c0, c1);
    __syncthreads();
    // P3: dual i=0
    ZACC; gemm32f(As, wmat + 2*16384, g, l15, c0, c1, acc);
    store_ssp(xi, acc, bimg + 2*128, r0, g, l15, c0, c1);
    ZACC; gemm32f(As, wmat + 5*16384, g, l15, c0, c1, acc);
    store_ssp(xj, acc, bimg + 5*128, r0, g, l15, c0, c1);
}

// ---------------- post: res_int x2 -> iWout -> res_at x2 -> (dual i+1) -> or-res ----------------
__global__ __launch_bounds__(256) void k_post(
    const short* __restrict__ wmat, const float* __restrict__ bimg,
    const float* __restrict__ mb, float* __restrict__ x,
    float* __restrict__ xo, float* __restrict__ xi, float* __restrict__ xj,
    int i, int dodual)
{
    __shared__ __align__(16) short As[4096];
    __shared__ __align__(16) short Ts[4096];
    const int tid = threadIdx.x, wv = tid>>6, ln = tid&63, g = ln>>4, l15 = ln&15;
    const int r0 = blockIdx.x*32;
    const int c0 = wv*32 + l15, c1 = c0 + 16;
    float xr[2][2][4];
    #pragma unroll
    for (int rt = 0; rt < 2; ++rt)
    #pragma unroll
    for (int r = 0; r < 4; ++r){
        size_t row = (size_t)(r0 + rt*16 + g*4 + r);
        xr[rt][0][r] = mb[row*FD + c0];
        xr[rt][1][r] = mb[row*FD + c1];
    }
    stage_A32(As, mb, r0, tid, true);
    __syncthreads();
    fx4 acc[2][2];
    // P1: irW1[i,0]
    ZACC; gemm32f(As, wmat + (size_t)(11+2*i)*16384, g, l15, c0, c1, acc);
    epi_ts(Ts, acc, bimg + (11+2*i)*128, g, l15, c0, c1);
    __syncthreads();
    // P2: irW2[i,0]
    ZACC; gemm32f(Ts, wmat + (size_t)(17+2*i)*16384, g, l15, c0, c1, acc);
    epi_xadd(xr, acc, bimg + (17+2*i)*128, c0, c1);
    write_xr(As, xr, g, l15, c0, c1);
    __syncthreads();
    // P3: irW1[i,1]
    ZACC; gemm32f(As, wmat + (size_t)(12+2*i)*16384, g, l15, c0, c1, acc);
    epi_ts(Ts, acc, bimg + (12+2*i)*128, g, l15, c0, c1);
    __syncthreads();
    // P4: irW2[i,1]
    ZACC; gemm32f(Ts, wmat + (size_t)(18+2*i)*16384, g, l15, c0, c1, acc);
    epi_xadd(xr, acc, bimg + (18+2*i)*128, c0, c1);
    write_xr(As, xr, g, l15, c0, c1);      // ssp(m_final)
    __syncthreads();
    // P5: iWout -> x = iu*xold + acc + b
    ZACC; gemm32f(As, wmat + (size_t)(8+i)*16384, g, l15, c0, c1, acc);
    {
        const float* bb = bimg + (8+i)*128;
        const float* uu = bimg + (41+i)*128;
        float b0 = bb[c0], b1 = bb[c1], u0 = uu[c0], u1 = uu[c1];
        #pragma unroll
        for (int rt = 0; rt < 2; ++rt)
        #pragma unroll
        for (int r = 0; r < 4; ++r){
            size_t row = (size_t)(r0 + rt*16 + g*4 + r);
            xr[rt][0][r] = u0*x[row*FD + c0] + acc[rt][0][r] + b0;
            xr[rt][1][r] = u1*x[row*FD + c1] + acc[rt][1][r] + b1;
        }
    }
    write_xr(Ts, xr, g, l15, c0, c1);      // ssp(x) -> Ts
    __syncthreads();
    // P6: arW1[i,0]
    ZACC; gemm32f(Ts, wmat + (size_t)(23+2*i)*16384, g, l15, c0, c1, acc);
    epi_ts(As, acc, bimg + (23+2*i)*128, g, l15, c0, c1);
    __syncthreads();
    // P7: arW2[i,0]
    ZACC; gemm32f(As, wmat + (size_t)(29+2*i)*16384, g, l15, c0, c1, acc);
    epi_xadd(xr, acc, bimg + (29+2*i)*128, c0, c1);
    write_xr(Ts, xr, g, l15, c0, c1);
    __syncthreads();
    // P8: arW1[i,1]
    ZACC; gemm32f(Ts, wmat + (size_t)(24+2*i)*16384, g, l15, c0, c1, acc);
    epi_ts(As, acc, bimg + (24+2*i)*128, g, l15, c0, c1);
    __syncthreads();
    // P9: arW2[i,1] -> x final
    ZACC; gemm32f(As, wmat + (size_t)(30+2*i)*16384, g, l15, c0, c1, acc);
    epi_xadd(xr, acc, bimg + (30+2*i)*128, c0, c1);
    store_xr(x, xr, r0, g, l15, c0, c1);
    write_xr(Ts, xr, g, l15, c0, c1);      // ssp(x)
    __syncthreads();
    // P10: dual(i+1) + orW1 (all read Ts)
    if (dodual){
        ZACC; gemm32f(Ts, wmat + (size_t)(3+i)*16384, g, l15, c0, c1, acc);
        store_ssp(xi, acc, bimg + (3+i)*128, r0, g, l15, c0, c1);
        ZACC; gemm32f(Ts, wmat + (size_t)(6+i)*16384, g, l15, c0, c1, acc);
        store_ssp(xj, acc, bimg + (6+i)*128, r0, g, l15, c0, c1);
    }
    ZACC; gemm32f(Ts, wmat + (size_t)(35+i)*16384, g, l15, c0, c1, acc);
    epi_ts(As, acc, bimg + (35+i)*128, g, l15, c0, c1);
    __syncthreads();
    // P11: orW2 -> xo = x + acc + b
    ZACC; gemm32f(As, wmat + (size_t)(38+i)*16384, g, l15, c0, c1, acc);
    {
        const float* bb = bimg + (38+i)*128;
        float b0 = bb[c0], b1 = bb[c1];
        #pragma unroll
        for (int rt = 0; rt < 2; ++rt)
        #pragma unroll
        for (int r = 0; r < 4; ++r){
            int row = r0 + rt*16 + g*4 + r;
            if (row < NA){
                xo[(size_t)row*FD + c0] = xr[rt][0][r] + acc[rt][0][r] + b0;
                xo[(size_t)row*FD + c1] = xr[rt][1][r] + acc[rt][1][r] + b1;
            }
        }
    }
}

// ---------------- message aggregation (unchanged) ----------------
__global__ __launch_bounds__(256) void k_agg_mfma(
    const short* __restrict__ rbf_bf, const short* __restrict__ wri,
    const int* __restrict__ idxj, const float* __restrict__ xi,
    const float* __restrict__ xj, float* __restrict__ mout)
{
    __shared__ short Rb[256*64];
    __shared__ short Wr[128*64];
    __shared__ int Jd[256];
    const int tid = threadIdx.x;
    const int wv = tid >> 6, ln = tid & 63;
    const int e0 = blockIdx.x * 256;
    {
        const char* g = (const char*)(rbf_bf + (size_t)e0*64);
        char* l = (char*)Rb;
        #pragma unroll
        for (int i = 0; i < 8; ++i){
            int off = wv*8192 + i*1024;
            gll16(g + off + ln*16, l + off);
        }
        const char* g2 = (const char*)wri;
        char* l2 = (char*)Wr;
        #pragma unroll
        for (int i = 0; i < 4; ++i){
            int off = wv*4096 + i*1024;
            gll16(g2 + off + ln*16, l2 + off);
        }
        Jd[tid] = idxj[e0 + tid];
    }
    __syncthreads();
    const int g = ln >> 4, l15 = ln & 15;
    bh8 a[4][2];
    #pragma unroll
    for (int mt = 0; mt < 4; ++mt){
        int el = wv*64 + mt*16 + l15;
        #pragma unroll
        for (int kk = 0; kk < 2; ++kk)
            a[mt][kk] = *(const bh8*)&Rb[el*64 + (((kk*4+g) ^ (el&7))*8)];
    }
    float pa[2][8];
    #pragma unroll
    for (int q = 0; q < 8; ++q){ pa[0][q]=0.f; pa[1][q]=0.f; }
    #pragma unroll
    for (int h = 0; h < 2; ++h){
        fx4 acc[4][4];
        #pragma unroll
        for (int mt = 0; mt < 4; ++mt)
            #pragma unroll
            for (int nt = 0; nt < 4; ++nt) acc[mt][nt] = (fx4){0,0,0,0};
        #pragma unroll
        for (int kk = 0; kk < 2; ++kk){
            #pragma unroll
            for (int nt = 0; nt < 4; ++nt){
                int n = h*64 + nt*16 + l15;
                bh8 b = *(const bh8*)&Wr[n*64 + (((kk*4+g) ^ (n&7))*8)];
                #pragma unroll
                for (int mt = 0; mt < 4; ++mt)
                    acc[mt][nt] = mfma16(a[mt][kk], b, acc[mt][nt]);
            }
        }
        #pragma unroll
        for (int mt = 0; mt < 4; ++mt){
            int at = mt >> 1;
            int jv[4];
            #pragma unroll
            for (int r = 0; r < 4; ++r) jv[r] = Jd[wv*64 + mt*16 + g*4 + r];
            #pragma unroll
            for (int nt = 0; nt < 4; ++nt){
                int col = h*64 + nt*16 + l15;
                float s = 0.f;
                #pragma unroll
                for (int r = 0; r < 4; ++r)
                    s += acc[mt][nt][r] * xj[(size_t)jv[r]*FD + col];
                pa[at][h*4+nt] += s;
            }
        }
    }
    #pragma unroll
    for (int at = 0; at < 2; ++at)
        #pragma unroll
        for (int q = 0; q < 8; ++q){
            float v = pa[at][q];
            v += __shfl_xor(v, 16);
            v += __shfl_xor(v, 32);
            pa[at][q] = v;
        }
    if (g == 0){
        #pragma unroll
        for (int at = 0; at < 2; ++at){
            int ga = blockIdx.x*8 + wv*2 + at;
            #pragma unroll
            for (int q = 0; q < 8; ++q){
                int col = (q>>2)*64 + (q&3)*16 + l15;
                mout[(size_t)ga*FD + col] = xi[(size_t)ga*FD + col] + pa[at][q];
            }
        }
    }
}

// ---------------- j=0: out4 = sum_i ssp(xo_i) @ oW_i[:, 0:4] ----------------
__global__ void k_out4all(const float* __restrict__ xo0, const float* __restrict__ xo1,
                          const float* __restrict__ xo2, const float* __restrict__ oW,
                          float* __restrict__ out4){
    int gid = blockIdx.x*256 + threadIdx.x;
    int a = gid >> 6;
    int lane = threadIdx.x & 63;
    if (a >= NA) return;
    float p0=0.f, p1=0.f, p2=0.f, p3=0.f;
    #pragma unroll
    for (int seg = 0; seg < 3; ++seg){
        const float* xo = (seg==0) ? xo0 : (seg==1) ? xo1 : xo2;
        const float* oWs = oW + (size_t)seg*FD*NOUTS_C;
        float y0 = sspf(xo[(size_t)a*FD + lane]);
        float y1 = sspf(xo[(size_t)a*FD + lane + 64]);
        const float* w0 = oWs + (size_t)lane*NOUTS_C;
        const float* w1 = oWs + (size_t)(lane+64)*NOUTS_C;
        p0 += y0*w0[0] + y1*w1[0];
        p1 += y0*w0[1] + y1*w1[1];
        p2 += y0*w0[2] + y1*w1[2];
        p3 += y0*w0[3] + y1*w1[3];
    }
    #pragma unroll
    for (int off = 32; off > 0; off >>= 1){
        p0 += __shfl_down(p0, off);
        p1 += __shfl_down(p1, off);
        p2 += __shfl_down(p2, off);
        p3 += __shfl_down(p3, off);
    }
    if (lane == 0){
        out4[a*4+0] = p0; out4[a*4+1] = p1;
        out4[a*4+2] = p2; out4[a*4+3] = p3;
    }
}

// ---------------- charge equilibration ----------------
__global__ void k_molsum(const float* __restrict__ out4, const int* __restrict__ mol,
                         float* __restrict__ sums){
    int a = blockIdx.x*256 + threadIdx.x;
    if (a >= NA) return;
    int m = mol[a];
    atomicAdd(&sums[m],     out4[a*4+0]);
    atomicAdd(&sums[64+m],  out4[a*4+1]);
    atomicAdd(&sums[128+m], out4[a*4+2]);
    atomicAdd(&sums[192+m], out4[a*4+3]);
}

__global__ void k_qaupd(const float* __restrict__ out4, const int* __restrict__ mol,
                        const float* __restrict__ sums, const float* __restrict__ QAmol,
                        const float* __restrict__ QBmol, float* __restrict__ QaA,
                        float* __restrict__ QaB){
    int a = blockIdx.x*256 + threadIdx.x;
    if (a >= NA) return;
    int m = mol[a];
    float qa_n = out4[a*4+0], fa = out4[a*4+1];
    float qb_n = out4[a*4+2], fb = out4[a*4+3];
    QaA[a] = qa_n + fa * ((QAmol[m] - sums[m])     / sums[64+m]);
    QaB[a] = qb_n + fb * ((QBmol[m] - sums[128+m]) / sums[192+m]);
}

// ---------------- A-image for final head: ssp(xo) bf16 swizzled, padded to 10048 ----------------
__global__ void k_prepA(const float* __restrict__ xo0, const float* __restrict__ xo1,
                        const float* __restrict__ xo2, short* __restrict__ Aimg){
    int gid = blockIdx.x*256 + threadIdx.x;   // 10048*48
    if (gid >= 10048*48) return;
    int row = gid / 48, s = gid - row*48;
    bh8 pk;
    if (row < NA){
        int seg = s >> 4, kl = (s & 15)*8;
        const float* src = ((seg==0) ? xo0 : (seg==1) ? xo1 : xo2) + (size_t)row*FD + kl;
        float4 u = *(const float4*)src;
        float4 v = *(const float4*)(src + 4);
        pk[0]=(short)f2bf(sspf(u.x)); pk[1]=(short)f2bf(sspf(u.y));
        pk[2]=(short)f2bf(sspf(u.z)); pk[3]=(short)f2bf(sspf(u.w));
        pk[4]=(short)f2bf(sspf(v.x)); pk[5]=(short)f2bf(sspf(v.y));
        pk[6]=(short)f2bf(sspf(v.z)); pk[7]=(short)f2bf(sspf(v.w));
    } else {
        #pragma unroll
        for (int j = 0; j < 8; ++j) pk[j] = 0;
    }
    *(bh8*)&Aimg[(size_t)row*384 + ((s ^ (row&7))*8)] = pk;
}

// ---------------- final head: grid(16 colgroups, 157 rowblocks), BM=64/BN=128/K=384 ----------------
__global__ __launch_bounds__(256) void k_final2(
    const short* __restrict__ Aimg, const short* __restrict__ oWimg,
    float* __restrict__ outp, float* __restrict__ nh_acc)
{
    __shared__ __align__(16) short As[64*384];     // 48 KB
    __shared__ __align__(16) short Bs[12*128*32];  // 96 KB
    const int tid = threadIdx.x, wv = tid>>6, ln = tid&63, g = ln>>4, l15 = ln&15;
    const int cg = blockIdx.x;
    const int a0 = blockIdx.y * 64;
    {
        const char* gA = (const char*)(Aimg + (size_t)a0*384);
        char* lA = (char*)As;
        #pragma unroll
        for (int i = 0; i < 12; ++i){
            int off = wv*12288 + i*1024;
            gll16(gA + off + ln*16, lA + off);
        }
        const char* gB = (const char*)oWimg;
        char* lB = (char*)Bs;
        #pragma unroll
        for (int kk = 0; kk < 12; ++kk)
            #pragma unroll
            for (int i = 0; i < 2; ++i){
                gll16(gB + kk*131072 + cg*8192 + wv*2048 + i*1024 + ln*16,
                      lB + kk*8192 + wv*2048 + i*1024);
            }
    }
    __syncthreads();
    const int arow = wv*16 + l15;
    fx4 osum[8], p2[8];
    #pragma unroll
    for (int nt = 0; nt < 8; ++nt){ osum[nt] = (fx4){0,0,0,0}; p2[nt] = (fx4){0,0,0,0}; }
    float nh = 0.f;
    for (int seg = 0; seg < 3; ++seg){
        fx4 acc[8];
        #pragma unroll
        for (int nt = 0; nt < 8; ++nt) acc[nt] = (fx4){0,0,0,0};
        #pragma unroll
        for (int kkl = 0; kkl < 4; ++kkl){
            int kk2 = seg*4 + kkl;
            int s = kk2*4 + g;
            bh8 a = *(const bh8*)&As[arow*384 + ((s ^ (arow&7))*8)];
            #pragma unroll
            for (int nt = 0; nt < 8; ++nt){
                int n = nt*16 + l15;
                bh8 b = *(const bh8*)&Bs[kk2*4096 + n*32 + ((g ^ (n&3))*8)];
                acc[nt] = mfma16(a, b, acc[nt]);
            }
        }
        #pragma unroll
        for (int nt = 0; nt < 8; ++nt)
        #pragma unroll
        for (int r = 0; r < 4; ++r){
            float o = acc[nt][r];
            osum[nt][r] += o;
            if (seg > 0){
                int A = a0 + wv*16 + g*4 + r;
                int col = cg*128 + nt*16 + l15;
                if (A >= 4 && A < NA && col < NOUTS_C){
                    float o2 = o*o;
                    float den = o2 + p2[nt][r] + 1e-7f;
                    float rr;
                    asm("v_rcp_f32 %0, %1" : "=v"(rr) : "v"(den));
                    nh += o2 * rr;
                }
            }
            p2[nt][r] = o*o;
        }
    }
    #pragma unroll
    for (int nt = 0; nt < 8; ++nt){
        int col = cg*128 + nt*16 + l15;
        #pragma unroll
        for (int r = 0; r < 4; ++r){
            int A = a0 + wv*16 + g*4 + r;
            if (A < NA && col >= 4 && col < NOUTS_C){
                float v = osum[nt][r];
                if (col > 4) v = fmaxf(v, 0.f);
                outp[(size_t)A*NOUT_FINAL + (col - 4)] = v;
            }
        }
    }
    #pragma unroll
    for (int off = 32; off > 0; off >>= 1) nh += __shfl_down(nh, off);
    if (ln == 0) atomicAdd(nh_acc, nh);
}

__global__ void k_finalize(const float* __restrict__ nh_acc, float* __restrict__ nh_out){
    *nh_out = *nh_acc * (1.0f / (float)((NA - 4) * NOUTS_C));
}

// =====================================================================
extern "C" void kernel_launch(void* const* d_in, const int* in_sizes, int n_in,
                              void* d_out, int out_size, void* d_ws, size_t ws_size,
                              hipStream_t stream)
{
    const float* R       = (const float*)d_in[0];
    const float* M       = (const float*)d_in[1];
    const float* QaAlpha = (const float*)d_in[2];
    const float* QaBeta  = (const float*)d_in[3];
    const float* em_W0   = (const float*)d_in[4];
    const float* em_b0   = (const float*)d_in[5];
    const float* em_W1   = (const float*)d_in[6];
    const float* em_b1   = (const float*)d_in[7];
    const float* em_W2   = (const float*)d_in[8];
    const float* em_b2   = (const float*)d_in[9];
    const float* iWrbf   = (const float*)d_in[10];
    const float* iWi     = (const float*)d_in[11];
    const float* ibi     = (const float*)d_in[12];
    const float* iWj     = (const float*)d_in[13];
    const float* ibj     = (const float*)d_in[14];
    const float* irW1    = (const float*)d_in[15];
    const float* irb1    = (const float*)d_in[16];
    const float* irW2    = (const float*)d_in[17];
    const float* irb2    = (const float*)d_in[18];
    const float* iWout   = (const float*)d_in[19];
    const float* ibout   = (const float*)d_in[20];
    const float* iu      = (const float*)d_in[21];
    const float* arW1    = (const float*)d_in[22];
    const float* arb1    = (const float*)d_in[23];
    const float* arW2    = (const float*)d_in[24];
    const float* arb2    = (const float*)d_in[25];
    const float* orW1    = (const float*)d_in[26];
    const float* orb1    = (const float*)d_in[27];
    const float* orW2    = (const float*)d_in[28];
    const float* orb2    = (const float*)d_in[29];
    const float* oW      = (const float*)d_in[30];
    const int*   Z       = (const int*)d_in[31];
    const int*   idx_i   = (const int*)d_in[32];
    const int*   idx_j   = (const int*)d_in[33];
    const int*   mol     = (const int*)d_in[34];

    float* out    = (float*)d_out;
    float* dij    = out + (size_t)NA*NOUT_FINAL;
    float* nh_out = dij + NE;

    float* fbase = (float*)d_ws;
    size_t fo = 0;
    float* x    = fbase + fo; fo += (size_t)NA*FD;
    float* xi   = fbase + fo; fo += (size_t)NA*FD;
    float* xj   = fbase + fo; fo += (size_t)NA*FD;
    float* mb   = fbase + fo; fo += (size_t)NA*FD;
    float* xo0  = fbase + fo; fo += (size_t)NA*FD;
    float* xo1  = fbase + fo; fo += (size_t)NA*FD;
    float* xo2  = fbase + fo; fo += (size_t)NA*FD;
    float* out4 = fbase + fo; fo += (size_t)NA*4;
    float* sums = fbase + fo; fo += 256;            // zero region start
    float* QAmol= fbase + fo; fo += 64;
    float* QBmol= fbase + fo; fo += 64;
    float* nhac = fbase + fo; fo += 1;              // zero region end
    float* QaA  = fbase + fo; fo += NA;
    float* QaB  = fbase + fo; fo += NA;
    float* bimg = fbase + fo; fo += 44*128;
    size_t sboff = ((fo*4 + 63) / 64) * 64;
    short* sbase = (short*)((char*)d_ws + sboff);
    size_t so = 0;
    short* rbf_bf = sbase + so; so += (size_t)NE*64;
    short* wmat   = sbase + so; so += (size_t)41*16384;
    short* wrbf   = sbase + so; so += (size_t)3*8192;
    short* oWimg  = sbase + so; so += (size_t)12*2048*32;
    short* Aimg   = sbase + so; so += (size_t)10048*384;

    hipMemsetAsync(sums, 0, (size_t)(256 + 64 + 64 + 1)*sizeof(float), stream);

    k_cvtW<<<(41*2048+255)/256, 256, 0, stream>>>(em_W1, em_W2, iWi, iWj, iWout,
                                                  irW1, irW2, arW1, arW2, orW1, orW2, wmat);
    k_cvtB<<<(44*128+255)/256, 256, 0, stream>>>(em_b1, em_b2, ibi, ibj, ibout,
                                                 irb1, irb2, arb1, arb2, orb1, orb2, iu, bimg);
    k_cvt_wrbf<<<(3*1024+255)/256, 256, 0, stream>>>(iWrbf, wrbf);
    k_cvt_oW<<<(12*2048*4)/256, 256, 0, stream>>>(oW, oWimg);

    k_dij<<<(NE+255)/256, 256, 0, stream>>>(R, idx_i, idx_j, dij);
    {
        double expn = exp(-10.0);
        float gamma = (float)pow(64.0/(2.0*(1.0-expn)), 2.0);
        float mu0 = (float)expn;
        float dmu = (float)((1.0-expn)/63.0);
        k_rbf_bf<<<(NE*32)/256, 256, 0, stream>>>(dij, rbf_bf, gamma, mu0, dmu);
    }
    k_init<<<(NA+255)/256, 256, 0, stream>>>(QaAlpha, QaBeta, mol, QaA, QaB, QAmol, QBmol);

    for (int j = 0; j <= 1; ++j){
        k_pre<<<313, 256, 0, stream>>>(wmat, bimg, Z, M, QaA, QaB, em_W0, em_b0, x, xi, xj);
        for (int i = 0; i < 3; ++i){
            k_agg_mfma<<<1250, 256, 0, stream>>>(rbf_bf, wrbf + (size_t)i*8192, idx_j, xi, xj, mb);
            float* xo = (i==0) ? xo0 : (i==1) ? xo1 : xo2;
            k_post<<<313, 256, 0, stream>>>(wmat, bimg, mb, x, xo, xi, xj, i, (i<2) ? 1 : 0);
        }
        if (j == 0){
            k_out4all<<<(NA*64)/256, 256, 0, stream>>>(xo0, xo1, xo2, oW, out4);
            k_molsum<<<(NA+255)/256, 256, 0, stream>>>(out4, mol, sums);
            k_qaupd<<<(NA+255)/256, 256, 0, stream>>>(out4, mol, sums, QAmol, QBmol, QaA, QaB);
        }
    }
    k_prepA<<<(10048*48)/256, 256, 0, stream>>>(xo0, xo1, xo2, Aimg);
    k_final2<<<dim3(16,157), 256, 0, stream>>>(Aimg, oWimg, out, nhac);
    k_finalize<<<1, 1, 0, stream>>>(nhac, nh_out);
}

// Round 4
// 982.914 us; speedup vs baseline: 2.4184x; 2.4184x over previous
//
#include <hip/hip_runtime.h>
#include <math.h>

#define NA 10000
#define FD 128
#define KR 64
#define DEGC 32
#define NE (NA*DEGC)
#define NOUTS_C 2005
#define NOUT_FINAL 2001

typedef __attribute__((ext_vector_type(8))) short bh8;
typedef __attribute__((ext_vector_type(4))) float fx4;

__device__ __forceinline__ float sspf(float x){
    float ex = __expf(-fabsf(x));
    return fmaxf(x, 0.0f) + __logf(1.0f + ex) - 0.6931471805599453f;
}
__device__ __forceinline__ unsigned short f2bf(float x){
    unsigned int u = __float_as_uint(x);
    unsigned int r = (u + 0x7fffu + ((u >> 16) & 1u)) >> 16;
    return (unsigned short)r;
}
__device__ __forceinline__ fx4 mfma16(bh8 a, bh8 b, fx4 c){
    return __builtin_amdgcn_mfma_f32_16x16x32_bf16(a, b, c, 0, 0, 0);
}
__device__ __forceinline__ void gll16(const void* g, void* l){
    __builtin_amdgcn_global_load_lds(
        (const __attribute__((address_space(1))) unsigned int*)g,
        (__attribute__((address_space(3))) unsigned int*)l, 16, 0, 0);
}

// ---------------- edge geometry ----------------
__global__ void k_dij(const float* __restrict__ R, const int* __restrict__ idx_i,
                      const int* __restrict__ idx_j, float* __restrict__ dij_out){
    int e = blockIdx.x*256 + threadIdx.x;
    if (e >= NE) return;
    int i = idx_i[e], j = idx_j[e];
    float dx = R[i*3+0] - R[j*3+0];
    float dy = R[i*3+1] - R[j*3+1];
    float dz = R[i*3+2] - R[j*3+2];
    dij_out[e] = sqrtf(fmaxf(dx*dx + dy*dy + dz*dz, 0.0f));
}

// rbf written as bf16 swizzled LDS-image rows [e][64k]  (for k_agg's gll16 staging)
__global__ void k_rbf_bf(const float* __restrict__ dij_in, short* __restrict__ rbf_bf,
                         float gamma, float mu0, float dmu){
    int gid = blockIdx.x*256 + threadIdx.x;   // NE*32
    int e = gid >> 5, kp = (gid & 31)*2;
    float d = dij_in[e];
    float t = d * 0.1f;
    float cut = 0.0f;
    if (d < 10.0f){
        float t2 = t*t, t3 = t2*t, t4 = t2*t2, t5 = t4*t;
        cut = 1.0f - 6.0f*t5 + 15.0f*t4 - 10.0f*t3;
    }
    float ed = expf(-d);
    float u0 = ed - (mu0 + (float)kp*dmu);
    float u1 = ed - (mu0 + (float)(kp+1)*dmu);
    float v0 = cut * expf(-gamma*u0*u0);
    float v1 = cut * expf(-gamma*u1*u1);
    unsigned int pk = (unsigned int)f2bf(v0) | ((unsigned int)f2bf(v1) << 16);
    int idx = e*64 + (((kp>>3) ^ (e&7))*8) + (kp&7);
    *(unsigned int*)&rbf_bf[idx] = pk;
}

// ---------------- init ----------------
__global__ void k_init(const float* __restrict__ QaAin, const float* __restrict__ QaBin,
                       const int* __restrict__ mol, float* __restrict__ QaA,
                       float* __restrict__ QaB, float* __restrict__ QAmol,
                       float* __restrict__ QBmol){
    int a = blockIdx.x*256 + threadIdx.x;
    if (a >= NA) return;
    float qa = QaAin[a], qb = QaBin[a];
    QaA[a] = qa; QaB[a] = qb;
    int m = mol[a];
    atomicAdd(&QAmol[m], qa);
    atomicAdd(&QBmol[m], qb);
}

// ---------------- weight conversion: fragment-linear streaming image ----------------
// per 128x128 matrix: frag f = ((cg*4+kk)*4+g)*16+l15 holds col n=cg*16+l15, k=(kk*4+g)*8..+7
__global__ void k_cvtW(const float* __restrict__ em_W1, const float* __restrict__ em_W2,
                       const float* __restrict__ iWi, const float* __restrict__ iWj,
                       const float* __restrict__ iWout, const float* __restrict__ irW1,
                       const float* __restrict__ irW2, const float* __restrict__ arW1,
                       const float* __restrict__ arW2, const float* __restrict__ orW1,
                       const float* __restrict__ orW2, short* __restrict__ img){
    int gid = blockIdx.x*256 + threadIdx.x;   // 41*2048 frags
    if (gid >= 41*2048) return;
    int m = gid >> 11;
    int f = gid & 2047;
    int l15 = f & 15, t = f >> 4;
    int g = t & 3, u = t >> 2;
    int kk = u & 3, cg = u >> 2;
    const float* src; int mm;
    if      (m < 1){ src = em_W1; mm = m; }
    else if (m < 2){ src = em_W2; mm = m-1; }
    else if (m < 5){ src = iWi;   mm = m-2; }
    else if (m < 8){ src = iWj;   mm = m-5; }
    else if (m < 11){ src = iWout; mm = m-8; }
    else if (m < 17){ src = irW1;  mm = m-11; }
    else if (m < 23){ src = irW2;  mm = m-17; }
    else if (m < 29){ src = arW1;  mm = m-23; }
    else if (m < 35){ src = arW2;  mm = m-29; }
    else if (m < 38){ src = orW1;  mm = m-35; }
    else            { src = orW2;  mm = m-38; }
    src += (size_t)mm * 16384;
    int n = cg*16 + l15;
    int k0 = (kk*4 + g)*8;
    bh8 pk;
    #pragma unroll
    for (int j = 0; j < 8; ++j) pk[j] = (short)f2bf(src[(k0+j)*128 + n]);
    *(bh8*)&img[m*16384 + f*8] = pk;
}

// biases + iu gathered into one image
__global__ void k_cvtB(const float* __restrict__ em_b1, const float* __restrict__ em_b2,
                       const float* __restrict__ ibi, const float* __restrict__ ibj,
                       const float* __restrict__ ibout, const float* __restrict__ irb1,
                       const float* __restrict__ irb2, const float* __restrict__ arb1,
                       const float* __restrict__ arb2, const float* __restrict__ orb1,
                       const float* __restrict__ orb2, const float* __restrict__ iu,
                       float* __restrict__ bimg){
    int gid = blockIdx.x*256 + threadIdx.x;  // 44*128
    if (gid >= 44*128) return;
    int m = gid >> 7, c = gid & 127;
    float v;
    if      (m < 1)  v = em_b1[c];
    else if (m < 2)  v = em_b2[c];
    else if (m < 5)  v = ibi[(m-2)*128+c];
    else if (m < 8)  v = ibj[(m-5)*128+c];
    else if (m < 11) v = ibout[(m-8)*128+c];
    else if (m < 17) v = irb1[(m-11)*128+c];
    else if (m < 23) v = irb2[(m-17)*128+c];
    else if (m < 29) v = arb1[(m-23)*128+c];
    else if (m < 35) v = arb2[(m-29)*128+c];
    else if (m < 38) v = orb1[(m-35)*128+c];
    else if (m < 41) v = orb2[(m-38)*128+c];
    else             v = iu[(m-41)*128+c];
    bimg[gid] = v;
}

// iWrbf [3][64][128] -> LDS-swizzle image (k_agg stages via gll16)
__global__ void k_cvt_wrbf(const float* __restrict__ iWrbf, short* __restrict__ img){
    int gid = blockIdx.x*256 + threadIdx.x;   // 3*1024
    if (gid >= 3*1024) return;
    int i = gid >> 10;
    int loc = gid & 1023;
    int n = loc >> 3, s = loc & 7;
    const float* src = iWrbf + (size_t)i*8192;
    int kbase = (s ^ (n&7)) * 8;
    bh8 pk;
    #pragma unroll
    for (int j = 0; j < 8; ++j) pk[j] = (short)f2bf(src[(kbase+j)*128 + n]);
    *(bh8*)&img[i*8192 + n*64 + s*8] = pk;
}

// oW [3][128][2005] -> image[kk][n][32k]
__global__ void k_cvt_oW(const float* __restrict__ oW, short* __restrict__ img){
    int gid = blockIdx.x*256 + threadIdx.x;   // 12*2048*4
    if (gid >= 12*2048*4) return;
    int kk = gid >> 13;
    int loc = gid & 8191;
    int n = loc >> 2, s = loc & 3;
    int seg = kk >> 2;
    int kbase = (s ^ (n&3)) * 8;
    bh8 pk;
    #pragma unroll
    for (int j = 0; j < 8; ++j){
        int kseg = (kk&3)*32 + kbase + j;
        float v = (n < NOUTS_C) ? oW[((size_t)seg*128 + kseg)*NOUTS_C + n] : 0.0f;
        pk[j] = (short)f2bf(v);
    }
    *(bh8*)&img[((size_t)kk*2048 + n)*32 + s*8] = pk;
}

// ================= BM=16 streaming-chain helpers =================
// A in LDS: As[row*128 + ((s ^ (row&7))*8) + (k&7)], s=k>>3
// W image: bh8 frag at ((cg*4+kk)*4+g)*16 + l15
__device__ __forceinline__ void gemm16s(const short* As, const short* __restrict__ W,
                                        int g, int l15, int wv, fx4 acc[2]){
    const bh8* Wf = (const bh8*)W;
    const int cgA = wv*2, cgB = wv*2 + 1;
    bh8 b[8];
    #pragma unroll
    for (int kk = 0; kk < 4; ++kk){
        b[kk]   = Wf[((cgA*4+kk)*4+g)*16 + l15];
        b[4+kk] = Wf[((cgB*4+kk)*4+g)*16 + l15];
    }
    #pragma unroll
    for (int kk = 0; kk < 4; ++kk){
        int q = kk*4 + g;
        bh8 a = *(const bh8*)&As[l15*128 + ((q ^ (l15&7))*8)];
        acc[0] = mfma16(a, b[kk],   acc[0]);
        acc[1] = mfma16(a, b[4+kk], acc[1]);
    }
}
#define ZACC2 { acc[0]=(fx4){0,0,0,0}; acc[1]=(fx4){0,0,0,0}; }

__device__ __forceinline__ void epiS_ts(short* dst, fx4 acc[2], const float* b,
                                        int g, int c0, int c1){
    float b0 = b[c0], b1 = b[c1];
    #pragma unroll
    for (int r = 0; r < 4; ++r){
        int row = g*4 + r;
        dst[row*128 + (((c0>>3) ^ (row&7))*8) + (c0&7)] = (short)f2bf(sspf(acc[0][r] + b0));
        dst[row*128 + (((c1>>3) ^ (row&7))*8) + (c1&7)] = (short)f2bf(sspf(acc[1][r] + b1));
    }
}
__device__ __forceinline__ void epiS_xadd(float xr[2][4], fx4 acc[2], const float* b,
                                          int c0, int c1){
    float b0 = b[c0], b1 = b[c1];
    #pragma unroll
    for (int r = 0; r < 4; ++r){
        xr[0][r] += acc[0][r] + b0;
        xr[1][r] += acc[1][r] + b1;
    }
}
__device__ __forceinline__ void writeS_xr(short* dst, float xr[2][4], int g, int c0, int c1){
    #pragma unroll
    for (int r = 0; r < 4; ++r){
        int row = g*4 + r;
        dst[row*128 + (((c0>>3) ^ (row&7))*8) + (c0&7)] = (short)f2bf(sspf(xr[0][r]));
        dst[row*128 + (((c1>>3) ^ (row&7))*8) + (c1&7)] = (short)f2bf(sspf(xr[1][r]));
    }
}
__device__ __forceinline__ void storeS_xr(float* dst, float xr[2][4], int r0, int g, int c0, int c1){
    #pragma unroll
    for (int r = 0; r < 4; ++r){
        int row = r0 + g*4 + r;
        dst[(size_t)row*FD + c0] = xr[0][r];
        dst[(size_t)row*FD + c1] = xr[1][r];
    }
}
__device__ __forceinline__ void storeS_ssp(float* dst, fx4 acc[2], const float* b,
                                           int r0, int g, int c0, int c1){
    float b0 = b[c0], b1 = b[c1];
    #pragma unroll
    for (int r = 0; r < 4; ++r){
        int row = r0 + g*4 + r;
        dst[(size_t)row*FD + c0] = sspf(acc[0][r] + b0);
        dst[(size_t)row*FD + c1] = sspf(acc[1][r] + b1);
    }
}
__device__ __forceinline__ void stage_A16(short* As, const float* src, int r0, int tid){
    int row = tid >> 4, cb = tid & 15;
    const float* p = src + (size_t)(r0+row)*FD + cb*8;
    float4 u = *(const float4*)p, v = *(const float4*)(p+4);
    float vv[8] = {u.x,u.y,u.z,u.w,v.x,v.y,v.z,v.w};
    bh8 pk;
    #pragma unroll
    for (int t = 0; t < 8; ++t) pk[t] = (short)f2bf(sspf(vv[t]));
    *(bh8*)&As[row*128 + ((cb ^ (row&7))*8)] = pk;
}

// ---------------- pre: embedding chain + dual(i=0), BM=16 ----------------
__global__ __launch_bounds__(256) void k_pre(
    const short* __restrict__ wimg, const float* __restrict__ bimg,
    const int* __restrict__ Z, const float* __restrict__ M,
    const float* __restrict__ QaA, const float* __restrict__ QaB,
    const float* __restrict__ em_W0, const float* __restrict__ em_b0,
    float* __restrict__ x, float* __restrict__ xi, float* __restrict__ xj)
{
    __shared__ __align__(16) short As[2048];
    __shared__ __align__(16) short Ts[2048];
    __shared__ float fs[16][4];
    const int tid = threadIdx.x, wv = tid>>6, ln = tid&63, g = ln>>4, l15 = ln&15;
    const int r0 = blockIdx.x*16;
    const int c0 = wv*32 + l15, c1 = c0 + 16;
    if (tid < 64){
        int rr = tid>>2, k = tid&3;
        int a = r0 + rr;
        fs[rr][k] = (k==0) ? (float)Z[a] : (k==1) ? M[a] : (k==2) ? QaA[a] : QaB[a];
    }
    __syncthreads();
    {   // h1 = ssp(f @ em_W0 + b0) -> As
        int row = tid>>4, cb = tid&15;
        bh8 pk;
        #pragma unroll
        for (int t = 0; t < 8; ++t){
            int c = cb*8 + t;
            float v = sspf(em_b0[c] + fs[row][0]*em_W0[c] + fs[row][1]*em_W0[128+c]
                           + fs[row][2]*em_W0[256+c] + fs[row][3]*em_W0[384+c]);
            pk[t] = (short)f2bf(v);
        }
        *(bh8*)&As[row*128 + ((cb ^ (row&7))*8)] = pk;
    }
    __syncthreads();
    fx4 acc[2];
    float xr[2][4];
    // P1: em_W1  As->Ts
    ZACC2; gemm16s(As, wimg + 0*16384, g, l15, wv, acc);
    epiS_ts(Ts, acc, bimg + 0*128, g, c0, c1);
    __syncthreads();
    // P2: em_W2  Ts -> x, As
    ZACC2; gemm16s(Ts, wimg + 1*16384, g, l15, wv, acc);
    {
        const float* b = bimg + 1*128;
        float b0 = b[c0], b1 = b[c1];
        #pragma unroll
        for (int r = 0; r < 4; ++r){
            xr[0][r] = acc[0][r] + b0;
            xr[1][r] = acc[1][r] + b1;
        }
    }
    storeS_xr(x, xr, r0, g, c0, c1);
    writeS_xr(As, xr, g, c0, c1);
    __syncthreads();
    // P3: dual i=0 reads As
    ZACC2; gemm16s(As, wimg + 2*16384, g, l15, wv, acc);
    storeS_ssp(xi, acc, bimg + 2*128, r0, g, c0, c1);
    ZACC2; gemm16s(As, wimg + 5*16384, g, l15, wv, acc);
    storeS_ssp(xj, acc, bimg + 5*128, r0, g, c0, c1);
}

// ---------------- post chain, BM=16 streaming ----------------
__global__ __launch_bounds__(256) void k_post(
    const short* __restrict__ wimg, const float* __restrict__ bimg,
    const float* __restrict__ mb, float* __restrict__ x,
    float* __restrict__ xo, float* __restrict__ xi, float* __restrict__ xj,
    int i, int dodual)
{
    __shared__ __align__(16) short As[2048];
    __shared__ __align__(16) short Ts[2048];
    const int tid = threadIdx.x, wv = tid>>6, ln = tid&63, g = ln>>4, l15 = ln&15;
    const int r0 = blockIdx.x*16;
    const int c0 = wv*32 + l15, c1 = c0 + 16;
    float xr[2][4];
    #pragma unroll
    for (int r = 0; r < 4; ++r){
        size_t row = (size_t)(r0 + g*4 + r);
        xr[0][r] = mb[row*FD + c0];
        xr[1][r] = mb[row*FD + c1];
    }
    stage_A16(As, mb, r0, tid);
    __syncthreads();
    fx4 acc[2];
    // P1: irW1[i,0]  As->Ts
    ZACC2; gemm16s(As, wimg + (size_t)(11+2*i)*16384, g, l15, wv, acc);
    epiS_ts(Ts, acc, bimg + (11+2*i)*128, g, c0, c1);
    __syncthreads();
    // P2: irW2[i,0]  Ts->As
    ZACC2; gemm16s(Ts, wimg + (size_t)(17+2*i)*16384, g, l15, wv, acc);
    epiS_xadd(xr, acc, bimg + (17+2*i)*128, c0, c1);
    writeS_xr(As, xr, g, c0, c1);
    __syncthreads();
    // P3: irW1[i,1]  As->Ts
    ZACC2; gemm16s(As, wimg + (size_t)(12+2*i)*16384, g, l15, wv, acc);
    epiS_ts(Ts, acc, bimg + (12+2*i)*128, g, c0, c1);
    __syncthreads();
    // P4: irW2[i,1]  Ts->As
    ZACC2; gemm16s(Ts, wimg + (size_t)(18+2*i)*16384, g, l15, wv, acc);
    epiS_xadd(xr, acc, bimg + (18+2*i)*128, c0, c1);
    writeS_xr(As, xr, g, c0, c1);
    __syncthreads();
    // P5: iWout  As->Ts ; xr = iu*xold + acc + b
    ZACC2; gemm16s(As, wimg + (size_t)(8+i)*16384, g, l15, wv, acc);
    {
        const float* bb = bimg + (8+i)*128;
        const float* uu = bimg + (41+i)*128;
        float b0 = bb[c0], b1 = bb[c1], u0 = uu[c0], u1 = uu[c1];
        #pragma unroll
        for (int r = 0; r < 4; ++r){
            size_t row = (size_t)(r0 + g*4 + r);
            xr[0][r] = u0*x[row*FD + c0] + acc[0][r] + b0;
            xr[1][r] = u1*x[row*FD + c1] + acc[1][r] + b1;
        }
    }
    writeS_xr(Ts, xr, g, c0, c1);
    __syncthreads();
    // P6: arW1[i,0]  Ts->As
    ZACC2; gemm16s(Ts, wimg + (size_t)(23+2*i)*16384, g, l15, wv, acc);
    epiS_ts(As, acc, bimg + (23+2*i)*128, g, c0, c1);
    __syncthreads();
    // P7: arW2[i,0]  As->Ts
    ZACC2; gemm16s(As, wimg + (size_t)(29+2*i)*16384, g, l15, wv, acc);
    epiS_xadd(xr, acc, bimg + (29+2*i)*128, c0, c1);
    writeS_xr(Ts, xr, g, c0, c1);
    __syncthreads();
    // P8: arW1[i,1]  Ts->As
    ZACC2; gemm16s(Ts, wimg + (size_t)(24+2*i)*16384, g, l15, wv, acc);
    epiS_ts(As, acc, bimg + (24+2*i)*128, g, c0, c1);
    __syncthreads();
    // P9: arW2[i,1]  As->Ts ; store x
    ZACC2; gemm16s(As, wimg + (size_t)(30+2*i)*16384, g, l15, wv, acc);
    epiS_xadd(xr, acc, bimg + (30+2*i)*128, c0, c1);
    storeS_xr(x, xr, r0, g, c0, c1);
    writeS_xr(Ts, xr, g, c0, c1);
    __syncthreads();
    // P10: duals + orW1 read Ts
    if (dodual){
        ZACC2; gemm16s(Ts, wimg + (size_t)(3+i)*16384, g, l15, wv, acc);
        storeS_ssp(xi, acc, bimg + (3+i)*128, r0, g, c0, c1);
        ZACC2; gemm16s(Ts, wimg + (size_t)(6+i)*16384, g, l15, wv, acc);
        storeS_ssp(xj, acc, bimg + (6+i)*128, r0, g, c0, c1);
    }
    ZACC2; gemm16s(Ts, wimg + (size_t)(35+i)*16384, g, l15, wv, acc);
    epiS_ts(As, acc, bimg + (35+i)*128, g, c0, c1);
    __syncthreads();
    // P11: orW2  As-> xo = xr + acc + b
    ZACC2; gemm16s(As, wimg + (size_t)(38+i)*16384, g, l15, wv, acc);
    {
        const float* bb = bimg + (38+i)*128;
        float b0 = bb[c0], b1 = bb[c1];
        #pragma unroll
        for (int r = 0; r < 4; ++r){
            int row = r0 + g*4 + r;
            xo[(size_t)row*FD + c0] = xr[0][r] + acc[0][r] + b0;
            xo[(size_t)row*FD + c1] = xr[1][r] + acc[1][r] + b1;
        }
    }
}

// ---------------- message aggregation (unchanged) ----------------
__global__ __launch_bounds__(256) void k_agg_mfma(
    const short* __restrict__ rbf_bf, const short* __restrict__ wri,
    const int* __restrict__ idxj, const float* __restrict__ xi,
    const float* __restrict__ xj, float* __restrict__ mout)
{
    __shared__ short Rb[256*64];
    __shared__ short Wr[128*64];
    __shared__ int Jd[256];
    const int tid = threadIdx.x;
    const int wv = tid >> 6, ln = tid & 63;
    const int e0 = blockIdx.x * 256;
    {
        const char* g = (const char*)(rbf_bf + (size_t)e0*64);
        char* l = (char*)Rb;
        #pragma unroll
        for (int i = 0; i < 8; ++i){
            int off = wv*8192 + i*1024;
            gll16(g + off + ln*16, l + off);
        }
        const char* g2 = (const char*)wri;
        char* l2 = (char*)Wr;
        #pragma unroll
        for (int i = 0; i < 4; ++i){
            int off = wv*4096 + i*1024;
            gll16(g2 + off + ln*16, l2 + off);
        }
        Jd[tid] = idxj[e0 + tid];
    }
    __syncthreads();
    const int g = ln >> 4, l15 = ln & 15;
    bh8 a[4][2];
    #pragma unroll
    for (int mt = 0; mt < 4; ++mt){
        int el = wv*64 + mt*16 + l15;
        #pragma unroll
        for (int kk = 0; kk < 2; ++kk)
            a[mt][kk] = *(const bh8*)&Rb[el*64 + (((kk*4+g) ^ (el&7))*8)];
    }
    float pa[2][8];
    #pragma unroll
    for (int q = 0; q < 8; ++q){ pa[0][q]=0.f; pa[1][q]=0.f; }
    #pragma unroll
    for (int h = 0; h < 2; ++h){
        fx4 acc[4][4];
        #pragma unroll
        for (int mt = 0; mt < 4; ++mt)
            #pragma unroll
            for (int nt = 0; nt < 4; ++nt) acc[mt][nt] = (fx4){0,0,0,0};
        #pragma unroll
        for (int kk = 0; kk < 2; ++kk){
            #pragma unroll
            for (int nt = 0; nt < 4; ++nt){
                int n = h*64 + nt*16 + l15;
                bh8 b = *(const bh8*)&Wr[n*64 + (((kk*4+g) ^ (n&7))*8)];
                #pragma unroll
                for (int mt = 0; mt < 4; ++mt)
                    acc[mt][nt] = mfma16(a[mt][kk], b, acc[mt][nt]);
            }
        }
        #pragma unroll
        for (int mt = 0; mt < 4; ++mt){
            int at = mt >> 1;
            int jv[4];
            #pragma unroll
            for (int r = 0; r < 4; ++r) jv[r] = Jd[wv*64 + mt*16 + g*4 + r];
            #pragma unroll
            for (int nt = 0; nt < 4; ++nt){
                int col = h*64 + nt*16 + l15;
                float s = 0.f;
                #pragma unroll
                for (int r = 0; r < 4; ++r)
                    s += acc[mt][nt][r] * xj[(size_t)jv[r]*FD + col];
                pa[at][h*4+nt] += s;
            }
        }
    }
    #pragma unroll
    for (int at = 0; at < 2; ++at)
        #pragma unroll
        for (int q = 0; q < 8; ++q){
            float v = pa[at][q];
            v += __shfl_xor(v, 16);
            v += __shfl_xor(v, 32);
            pa[at][q] = v;
        }
    if (g == 0){
        #pragma unroll
        for (int at = 0; at < 2; ++at){
            int ga = blockIdx.x*8 + wv*2 + at;
            #pragma unroll
            for (int q = 0; q < 8; ++q){
                int col = (q>>2)*64 + (q&3)*16 + l15;
                mout[(size_t)ga*FD + col] = xi[(size_t)ga*FD + col] + pa[at][q];
            }
        }
    }
}

// ---------------- j=0: out4 = sum_i ssp(xo_i) @ oW_i[:, 0:4] ----------------
__global__ void k_out4all(const float* __restrict__ xo0, const float* __restrict__ xo1,
                          const float* __restrict__ xo2, const float* __restrict__ oW,
                          float* __restrict__ out4){
    int gid = blockIdx.x*256 + threadIdx.x;
    int a = gid >> 6;
    int lane = threadIdx.x & 63;
    if (a >= NA) return;
    float p0=0.f, p1=0.f, p2=0.f, p3=0.f;
    #pragma unroll
    for (int seg = 0; seg < 3; ++seg){
        const float* xo = (seg==0) ? xo0 : (seg==1) ? xo1 : xo2;
        const float* oWs = oW + (size_t)seg*FD*NOUTS_C;
        float y0 = sspf(xo[(size_t)a*FD + lane]);
        float y1 = sspf(xo[(size_t)a*FD + lane + 64]);
        const float* w0 = oWs + (size_t)lane*NOUTS_C;
        const float* w1 = oWs + (size_t)(lane+64)*NOUTS_C;
        p0 += y0*w0[0] + y1*w1[0];
        p1 += y0*w0[1] + y1*w1[1];
        p2 += y0*w0[2] + y1*w1[2];
        p3 += y0*w0[3] + y1*w1[3];
    }
    #pragma unroll
    for (int off = 32; off > 0; off >>= 1){
        p0 += __shfl_down(p0, off);
        p1 += __shfl_down(p1, off);
        p2 += __shfl_down(p2, off);
        p3 += __shfl_down(p3, off);
    }
    if (lane == 0){
        out4[a*4+0] = p0; out4[a*4+1] = p1;
        out4[a*4+2] = p2; out4[a*4+3] = p3;
    }
}

// ---------------- charge equilibration ----------------
__global__ void k_molsum(const float* __restrict__ out4, const int* __restrict__ mol,
                         float* __restrict__ sums){
    int a = blockIdx.x*256 + threadIdx.x;
    if (a >= NA) return;
    int m = mol[a];
    atomicAdd(&sums[m],     out4[a*4+0]);
    atomicAdd(&sums[64+m],  out4[a*4+1]);
    atomicAdd(&sums[128+m], out4[a*4+2]);
    atomicAdd(&sums[192+m], out4[a*4+3]);
}

__global__ void k_qaupd(const float* __restrict__ out4, const int* __restrict__ mol,
                        const float* __restrict__ sums, const float* __restrict__ QAmol,
                        const float* __restrict__ QBmol, float* __restrict__ QaA,
                        float* __restrict__ QaB){
    int a = blockIdx.x*256 + threadIdx.x;
    if (a >= NA) return;
    int m = mol[a];
    float qa_n = out4[a*4+0], fa = out4[a*4+1];
    float qb_n = out4[a*4+2], fb = out4[a*4+3];
    QaA[a] = qa_n + fa * ((QAmol[m] - sums[m])     / sums[64+m]);
    QaB[a] = qb_n + fb * ((QBmol[m] - sums[128+m]) / sums[192+m]);
}

// ---------------- A-image for final head ----------------
__global__ void k_prepA(const float* __restrict__ xo0, const float* __restrict__ xo1,
                        const float* __restrict__ xo2, short* __restrict__ Aimg){
    int gid = blockIdx.x*256 + threadIdx.x;   // 10048*48
    if (gid >= 10048*48) return;
    int row = gid / 48, s = gid - row*48;
    bh8 pk;
    if (row < NA){
        int seg = s >> 4, kl = (s & 15)*8;
        const float* src = ((seg==0) ? xo0 : (seg==1) ? xo1 : xo2) + (size_t)row*FD + kl;
        float4 u = *(const float4*)src;
        float4 v = *(const float4*)(src + 4);
        pk[0]=(short)f2bf(sspf(u.x)); pk[1]=(short)f2bf(sspf(u.y));
        pk[2]=(short)f2bf(sspf(u.z)); pk[3]=(short)f2bf(sspf(u.w));
        pk[4]=(short)f2bf(sspf(v.x)); pk[5]=(short)f2bf(sspf(v.y));
        pk[6]=(short)f2bf(sspf(v.z)); pk[7]=(short)f2bf(sspf(v.w));
    } else {
        #pragma unroll
        for (int j = 0; j < 8; ++j) pk[j] = 0;
    }
    *(bh8*)&Aimg[(size_t)row*384 + ((s ^ (row&7))*8)] = pk;
}

// ---------------- final head ----------------
__global__ __launch_bounds__(256) void k_final2(
    const short* __restrict__ Aimg, const short* __restrict__ oWimg,
    float* __restrict__ outp, float* __restrict__ nh_acc)
{
    __shared__ __align__(16) short As[64*384];     // 48 KB
    __shared__ __align__(16) short Bs[12*128*32];  // 96 KB
    const int tid = threadIdx.x, wv = tid>>6, ln = tid&63, g = ln>>4, l15 = ln&15;
    const int cg = blockIdx.x;
    const int a0 = blockIdx.y * 64;
    {
        const char* gA = (const char*)(Aimg + (size_t)a0*384);
        char* lA = (char*)As;
        #pragma unroll
        for (int i = 0; i < 12; ++i){
            int off = wv*12288 + i*1024;
            gll16(gA + off + ln*16, lA + off);
        }
        const char* gB = (const char*)oWimg;
        char* lB = (char*)Bs;
        #pragma unroll
        for (int kk = 0; kk < 12; ++kk)
            #pragma unroll
            for (int i = 0; i < 2; ++i){
                gll16(gB + kk*131072 + cg*8192 + wv*2048 + i*1024 + ln*16,
                      lB + kk*8192 + wv*2048 + i*1024);
            }
    }
    __syncthreads();
    const int arow = wv*16 + l15;
    fx4 osum[8], p2[8];
    #pragma unroll
    for (int nt = 0; nt < 8; ++nt){ osum[nt] = (fx4){0,0,0,0}; p2[nt] = (fx4){0,0,0,0}; }
    float nh = 0.f;
    for (int seg = 0; seg < 3; ++seg){
        fx4 acc[8];
        #pragma unroll
        for (int nt = 0; nt < 8; ++nt) acc[nt] = (fx4){0,0,0,0};
        #pragma unroll
        for (int kkl = 0; kkl < 4; ++kkl){
            int kk2 = seg*4 + kkl;
            int s = kk2*4 + g;
            bh8 a = *(const bh8*)&As[arow*384 + ((s ^ (arow&7))*8)];
            #pragma unroll
            for (int nt = 0; nt < 8; ++nt){
                int n = nt*16 + l15;
                bh8 b = *(const bh8*)&Bs[kk2*4096 + n*32 + ((g ^ (n&3))*8)];
                acc[nt] = mfma16(a, b, acc[nt]);
            }
        }
        #pragma unroll
        for (int nt = 0; nt < 8; ++nt)
        #pragma unroll
        for (int r = 0; r < 4; ++r){
            float o = acc[nt][r];
            osum[nt][r] += o;
            if (seg > 0){
                int A = a0 + wv*16 + g*4 + r;
                int col = cg*128 + nt*16 + l15;
                if (A >= 4 && A < NA && col < NOUTS_C){
                    float o2 = o*o;
                    float den = o2 + p2[nt][r] + 1e-7f;
                    float rr;
                    asm("v_rcp_f32 %0, %1" : "=v"(rr) : "v"(den));
                    nh += o2 * rr;
                }
            }
            p2[nt][r] = o*o;
        }
    }
    #pragma unroll
    for (int nt = 0; nt < 8; ++nt){
        int col = cg*128 + nt*16 + l15;
        #pragma unroll
        for (int r = 0; r < 4; ++r){
            int A = a0 + wv*16 + g*4 + r;
            if (A < NA && col >= 4 && col < NOUTS_C){
                float v = osum[nt][r];
                if (col > 4) v = fmaxf(v, 0.f);
                outp[(size_t)A*NOUT_FINAL + (col - 4)] = v;
            }
        }
    }
    #pragma unroll
    for (int off = 32; off > 0; off >>= 1) nh += __shfl_down(nh, off);
    if (ln == 0) atomicAdd(nh_acc, nh);
}

__global__ void k_finalize(const float* __restrict__ nh_acc, float* __restrict__ nh_out){
    *nh_out = *nh_acc * (1.0f / (float)((NA - 4) * NOUTS_C));
}

// =====================================================================
extern "C" void kernel_launch(void* const* d_in, const int* in_sizes, int n_in,
                              void* d_out, int out_size, void* d_ws, size_t ws_size,
                              hipStream_t stream)
{
    const float* R       = (const float*)d_in[0];
    const float* M       = (const float*)d_in[1];
    const float* QaAlpha = (const float*)d_in[2];
    const float* QaBeta  = (const float*)d_in[3];
    const float* em_W0   = (const float*)d_in[4];
    const float* em_b0   = (const float*)d_in[5];
    const float* em_W1   = (const float*)d_in[6];
    const float* em_b1   = (const float*)d_in[7];
    const float* em_W2   = (const float*)d_in[8];
    const float* em_b2   = (const float*)d_in[9];
    const float* iWrbf   = (const float*)d_in[10];
    const float* iWi     = (const float*)d_in[11];
    const float* ibi     = (const float*)d_in[12];
    const float* iWj     = (const float*)d_in[13];
    const float* ibj     = (const float*)d_in[14];
    const float* irW1    = (const float*)d_in[15];
    const float* irb1    = (const float*)d_in[16];
    const float* irW2    = (const float*)d_in[17];
    const float* irb2    = (const float*)d_in[18];
    const float* iWout   = (const float*)d_in[19];
    const float* ibout   = (const float*)d_in[20];
    const float* iu      = (const float*)d_in[21];
    const float* arW1    = (const float*)d_in[22];
    const float* arb1    = (const float*)d_in[23];
    const float* arW2    = (const float*)d_in[24];
    const float* arb2    = (const float*)d_in[25];
    const float* orW1    = (const float*)d_in[26];
    const float* orb1    = (const float*)d_in[27];
    const float* orW2    = (const float*)d_in[28];
    const float* orb2    = (const float*)d_in[29];
    const float* oW      = (const float*)d_in[30];
    const int*   Z       = (const int*)d_in[31];
    const int*   idx_i   = (const int*)d_in[32];
    const int*   idx_j   = (const int*)d_in[33];
    const int*   mol     = (const int*)d_in[34];

    float* out    = (float*)d_out;
    float* dij    = out + (size_t)NA*NOUT_FINAL;
    float* nh_out = dij + NE;

    float* fbase = (float*)d_ws;
    size_t fo = 0;
    float* x    = fbase + fo; fo += (size_t)NA*FD;
    float* xi   = fbase + fo; fo += (size_t)NA*FD;
    float* xj   = fbase + fo; fo += (size_t)NA*FD;
    float* mb   = fbase + fo; fo += (size_t)NA*FD;
    float* xo0  = fbase + fo; fo += (size_t)NA*FD;
    float* xo1  = fbase + fo; fo += (size_t)NA*FD;
    float* xo2  = fbase + fo; fo += (size_t)NA*FD;
    float* out4 = fbase + fo; fo += (size_t)NA*4;
    float* sums = fbase + fo; fo += 256;            // zero region start
    float* QAmol= fbase + fo; fo += 64;
    float* QBmol= fbase + fo; fo += 64;
    float* nhac = fbase + fo; fo += 1;              // zero region end
    float* QaA  = fbase + fo; fo += NA;
    float* QaB  = fbase + fo; fo += NA;
    float* bimg = fbase + fo; fo += 44*128;
    size_t sboff = ((fo*4 + 63) / 64) * 64;
    short* sbase = (short*)((char*)d_ws + sboff);
    size_t so = 0;
    short* rbf_bf = sbase + so; so += (size_t)NE*64;
    short* wimg   = sbase + so; so += (size_t)41*16384;
    short* wrbf   = sbase + so; so += (size_t)3*8192;
    short* oWimg  = sbase + so; so += (size_t)12*2048*32;
    short* Aimg   = sbase + so; so += (size_t)10048*384;

    hipMemsetAsync(sums, 0, (size_t)(256 + 64 + 64 + 1)*sizeof(float), stream);

    k_cvtW<<<(41*2048+255)/256, 256, 0, stream>>>(em_W1, em_W2, iWi, iWj, iWout,
                                                  irW1, irW2, arW1, arW2, orW1, orW2, wimg);
    k_cvtB<<<(44*128+255)/256, 256, 0, stream>>>(em_b1, em_b2, ibi, ibj, ibout,
                                                 irb1, irb2, arb1, arb2, orb1, orb2, iu, bimg);
    k_cvt_wrbf<<<(3*1024+255)/256, 256, 0, stream>>>(iWrbf, wrbf);
    k_cvt_oW<<<(12*2048*4)/256, 256, 0, stream>>>(oW, oWimg);

    k_dij<<<(NE+255)/256, 256, 0, stream>>>(R, idx_i, idx_j, dij);
    {
        double expn = exp(-10.0);
        float gamma = (float)pow(64.0/(2.0*(1.0-expn)), 2.0);
        float mu0 = (float)expn;
        float dmu = (float)((1.0-expn)/63.0);
        k_rbf_bf<<<(NE*32)/256, 256, 0, stream>>>(dij, rbf_bf, gamma, mu0, dmu);
    }
    k_init<<<(NA+255)/256, 256, 0, stream>>>(QaAlpha, QaBeta, mol, QaA, QaB, QAmol, QBmol);

    for (int j = 0; j <= 1; ++j){
        k_pre<<<625, 256, 0, stream>>>(wimg, bimg, Z, M, QaA, QaB, em_W0, em_b0, x, xi, xj);
        for (int i = 0; i < 3; ++i){
            k_agg_mfma<<<1250, 256, 0, stream>>>(rbf_bf, wrbf + (size_t)i*8192, idx_j, xi, xj, mb);
            float* xo = (i==0) ? xo0 : (i==1) ? xo1 : xo2;
            k_post<<<625, 256, 0, stream>>>(wimg, bimg, mb, x, xo, xi, xj, i, (i<2) ? 1 : 0);
        }
        if (j == 0){
            k_out4all<<<(NA*64)/256, 256, 0, stream>>>(xo0, xo1, xo2, oW, out4);
            k_molsum<<<(NA+255)/256, 256, 0, stream>>>(out4, mol, sums);
            k_qaupd<<<(NA+255)/256, 256, 0, stream>>>(out4, mol, sums, QAmol, QBmol, QaA, QaB);
        }
    }
    k_prepA<<<(10048*48)/256, 256, 0, stream>>>(xo0, xo1, xo2, Aimg);
    k_final2<<<dim3(16,157), 256, 0, stream>>>(Aimg, oWimg, out, nhac);
    k_finalize<<<1, 1, 0, stream>>>(nhac, nh_out);
}

// Round 5
// 963.573 us; speedup vs baseline: 2.4669x; 1.0201x over previous
//
#include <hip/hip_runtime.h>
#include <math.h>

#define NA 10000
#define FD 128
#define KR 64
#define DEGC 32
#define NE (NA*DEGC)
#define NOUTS_C 2005
#define NOUT_FINAL 2001

typedef __attribute__((ext_vector_type(8))) short bh8;
typedef __attribute__((ext_vector_type(4))) float fx4;

__device__ __forceinline__ float sspf(float x){
    float ex = __expf(-fabsf(x));
    return fmaxf(x, 0.0f) + __logf(1.0f + ex) - 0.6931471805599453f;
}
__device__ __forceinline__ unsigned short f2bf(float x){
    unsigned int u = __float_as_uint(x);
    unsigned int r = (u + 0x7fffu + ((u >> 16) & 1u)) >> 16;
    return (unsigned short)r;
}
__device__ __forceinline__ float bf2f(unsigned short u){
    return __uint_as_float(((unsigned int)u) << 16);
}
__device__ __forceinline__ fx4 mfma16(bh8 a, bh8 b, fx4 c){
    return __builtin_amdgcn_mfma_f32_16x16x32_bf16(a, b, c, 0, 0, 0);
}
__device__ __forceinline__ void gll16(const void* g, void* l){
    __builtin_amdgcn_global_load_lds(
        (const __attribute__((address_space(1))) unsigned int*)g,
        (__attribute__((address_space(3))) unsigned int*)l, 16, 0, 0);
}

// ---------------- edge geometry ----------------
__global__ void k_dij(const float* __restrict__ R, const int* __restrict__ idx_i,
                      const int* __restrict__ idx_j, float* __restrict__ dij_out){
    int e = blockIdx.x*256 + threadIdx.x;
    if (e >= NE) return;
    int i = idx_i[e], j = idx_j[e];
    float dx = R[i*3+0] - R[j*3+0];
    float dy = R[i*3+1] - R[j*3+1];
    float dz = R[i*3+2] - R[j*3+2];
    dij_out[e] = sqrtf(fmaxf(dx*dx + dy*dy + dz*dz, 0.0f));
}

// ---------------- init ----------------
__global__ void k_init(const float* __restrict__ QaAin, const float* __restrict__ QaBin,
                       const int* __restrict__ mol, float* __restrict__ QaA,
                       float* __restrict__ QaB, float* __restrict__ QAmol,
                       float* __restrict__ QBmol){
    int a = blockIdx.x*256 + threadIdx.x;
    if (a >= NA) return;
    float qa = QaAin[a], qb = QaBin[a];
    QaA[a] = qa; QaB[a] = qb;
    int m = mol[a];
    atomicAdd(&QAmol[m], qa);
    atomicAdd(&QBmol[m], qb);
}

// ---------------- weight conversion: fragment-linear streaming image ----------------
__global__ void k_cvtW(const float* __restrict__ em_W1, const float* __restrict__ em_W2,
                       const float* __restrict__ iWi, const float* __restrict__ iWj,
                       const float* __restrict__ iWout, const float* __restrict__ irW1,
                       const float* __restrict__ irW2, const float* __restrict__ arW1,
                       const float* __restrict__ arW2, const float* __restrict__ orW1,
                       const float* __restrict__ orW2, short* __restrict__ img){
    int gid = blockIdx.x*256 + threadIdx.x;   // 41*2048 frags
    if (gid >= 41*2048) return;
    int m = gid >> 11;
    int f = gid & 2047;
    int l15 = f & 15, t = f >> 4;
    int g = t & 3, u = t >> 2;
    int kk = u & 3, cg = u >> 2;
    const float* src; int mm;
    if      (m < 1){ src = em_W1; mm = m; }
    else if (m < 2){ src = em_W2; mm = m-1; }
    else if (m < 5){ src = iWi;   mm = m-2; }
    else if (m < 8){ src = iWj;   mm = m-5; }
    else if (m < 11){ src = iWout; mm = m-8; }
    else if (m < 17){ src = irW1;  mm = m-11; }
    else if (m < 23){ src = irW2;  mm = m-17; }
    else if (m < 29){ src = arW1;  mm = m-23; }
    else if (m < 35){ src = arW2;  mm = m-29; }
    else if (m < 38){ src = orW1;  mm = m-35; }
    else            { src = orW2;  mm = m-38; }
    src += (size_t)mm * 16384;
    int n = cg*16 + l15;
    int k0 = (kk*4 + g)*8;
    bh8 pk;
    #pragma unroll
    for (int j = 0; j < 8; ++j) pk[j] = (short)f2bf(src[(k0+j)*128 + n]);
    *(bh8*)&img[m*16384 + f*8] = pk;
}

// biases + iu gathered into one image
__global__ void k_cvtB(const float* __restrict__ em_b1, const float* __restrict__ em_b2,
                       const float* __restrict__ ibi, const float* __restrict__ ibj,
                       const float* __restrict__ ibout, const float* __restrict__ irb1,
                       const float* __restrict__ irb2, const float* __restrict__ arb1,
                       const float* __restrict__ arb2, const float* __restrict__ orb1,
                       const float* __restrict__ orb2, const float* __restrict__ iu,
                       float* __restrict__ bimg){
    int gid = blockIdx.x*256 + threadIdx.x;  // 44*128
    if (gid >= 44*128) return;
    int m = gid >> 7, c = gid & 127;
    float v;
    if      (m < 1)  v = em_b1[c];
    else if (m < 2)  v = em_b2[c];
    else if (m < 5)  v = ibi[(m-2)*128+c];
    else if (m < 8)  v = ibj[(m-5)*128+c];
    else if (m < 11) v = ibout[(m-8)*128+c];
    else if (m < 17) v = irb1[(m-11)*128+c];
    else if (m < 23) v = irb2[(m-17)*128+c];
    else if (m < 29) v = arb1[(m-23)*128+c];
    else if (m < 35) v = arb2[(m-29)*128+c];
    else if (m < 38) v = orb1[(m-35)*128+c];
    else if (m < 41) v = orb2[(m-38)*128+c];
    else             v = iu[(m-41)*128+c];
    bimg[gid] = v;
}

// iWrbf [3][64][128] -> LDS-swizzle image (k_agg stages via gll16)
__global__ void k_cvt_wrbf(const float* __restrict__ iWrbf, short* __restrict__ img){
    int gid = blockIdx.x*256 + threadIdx.x;   // 3*1024
    if (gid >= 3*1024) return;
    int i = gid >> 10;
    int loc = gid & 1023;
    int n = loc >> 3, s = loc & 7;
    const float* src = iWrbf + (size_t)i*8192;
    int kbase = (s ^ (n&7)) * 8;
    bh8 pk;
    #pragma unroll
    for (int j = 0; j < 8; ++j) pk[j] = (short)f2bf(src[(kbase+j)*128 + n]);
    *(bh8*)&img[i*8192 + n*64 + s*8] = pk;
}

// oW [3][128][2005] -> frag-linear image: frag f = (((cg*12+kk2)*8+nt)*4+g)*16+l15
// holds col n=cg*128+nt*16+l15 (pad->0), k = kk2*32 + g*8 + j  (seg = kk2>>2)
__global__ void k_cvt_oW(const float* __restrict__ oW, short* __restrict__ img){
    int gid = blockIdx.x*256 + threadIdx.x;   // 98304 frags
    if (gid >= 98304) return;
    int l15 = gid & 15;
    int g = (gid >> 4) & 3;
    int nt = (gid >> 6) & 7;
    int rest = gid >> 9;
    int kk2 = rest % 12, cg = rest / 12;
    int seg = kk2 >> 2;
    int n = cg*128 + nt*16 + l15;
    int kbase = (kk2 & 3)*32 + g*8;
    bh8 pk;
    #pragma unroll
    for (int j = 0; j < 8; ++j){
        float v = (n < NOUTS_C) ? oW[((size_t)seg*128 + kbase + j)*NOUTS_C + n] : 0.0f;
        pk[j] = (short)f2bf(v);
    }
    *(bh8*)&img[(size_t)gid*8] = pk;
}

// ================= BM=16 streaming-chain helpers =================
__device__ __forceinline__ void loadB8(const short* __restrict__ W, int g, int l15, int wv, bh8 b[8]){
    const bh8* Wf = (const bh8*)W;
    const int cgA = wv*2, cgB = wv*2 + 1;
    #pragma unroll
    for (int kk = 0; kk < 4; ++kk){
        b[kk]   = Wf[((cgA*4+kk)*4+g)*16 + l15];
        b[4+kk] = Wf[((cgB*4+kk)*4+g)*16 + l15];
    }
}
__device__ __forceinline__ void gemmB(const short* As, const bh8 b[8], int g, int l15, fx4 acc[2]){
    #pragma unroll
    for (int kk = 0; kk < 4; ++kk){
        int q = kk*4 + g;
        bh8 a = *(const bh8*)&As[l15*128 + ((q ^ (l15&7))*8)];
        acc[0] = mfma16(a, b[kk],   acc[0]);
        acc[1] = mfma16(a, b[4+kk], acc[1]);
    }
}
#define ZACC2 { acc[0]=(fx4){0,0,0,0}; acc[1]=(fx4){0,0,0,0}; }

__device__ __forceinline__ void epiS_ts(short* dst, fx4 acc[2], const float* b,
                                        int g, int c0, int c1){
    float b0 = b[c0], b1 = b[c1];
    #pragma unroll
    for (int r = 0; r < 4; ++r){
        int row = g*4 + r;
        dst[row*128 + (((c0>>3) ^ (row&7))*8) + (c0&7)] = (short)f2bf(sspf(acc[0][r] + b0));
        dst[row*128 + (((c1>>3) ^ (row&7))*8) + (c1&7)] = (short)f2bf(sspf(acc[1][r] + b1));
    }
}
__device__ __forceinline__ void epiS_xadd(float xr[2][4], fx4 acc[2], const float* b,
                                          int c0, int c1){
    float b0 = b[c0], b1 = b[c1];
    #pragma unroll
    for (int r = 0; r < 4; ++r){
        xr[0][r] += acc[0][r] + b0;
        xr[1][r] += acc[1][r] + b1;
    }
}
__device__ __forceinline__ void writeS_xr(short* dst, float xr[2][4], int g, int c0, int c1){
    #pragma unroll
    for (int r = 0; r < 4; ++r){
        int row = g*4 + r;
        dst[row*128 + (((c0>>3) ^ (row&7))*8) + (c0&7)] = (short)f2bf(sspf(xr[0][r]));
        dst[row*128 + (((c1>>3) ^ (row&7))*8) + (c1&7)] = (short)f2bf(sspf(xr[1][r]));
    }
}
__device__ __forceinline__ void storeS_xr(float* dst, float xr[2][4], int r0, int g, int c0, int c1){
    #pragma unroll
    for (int r = 0; r < 4; ++r){
        int row = r0 + g*4 + r;
        dst[(size_t)row*FD + c0] = xr[0][r];
        dst[(size_t)row*FD + c1] = xr[1][r];
    }
}
__device__ __forceinline__ void storeS_ssp(float* dst, fx4 acc[2], const float* b,
                                           int r0, int g, int c0, int c1){
    float b0 = b[c0], b1 = b[c1];
    #pragma unroll
    for (int r = 0; r < 4; ++r){
        int row = r0 + g*4 + r;
        dst[(size_t)row*FD + c0] = sspf(acc[0][r] + b0);
        dst[(size_t)row*FD + c1] = sspf(acc[1][r] + b1);
    }
}
__device__ __forceinline__ void stage_A16(short* As, const float* src, int r0, int tid){
    int row = tid >> 4, cb = tid & 15;
    const float* p = src + (size_t)(r0+row)*FD + cb*8;
    float4 u = *(const float4*)p, v = *(const float4*)(p+4);
    float vv[8] = {u.x,u.y,u.z,u.w,v.x,v.y,v.z,v.w};
    bh8 pk;
    #pragma unroll
    for (int t = 0; t < 8; ++t) pk[t] = (short)f2bf(sspf(vv[t]));
    *(bh8*)&As[row*128 + ((cb ^ (row&7))*8)] = pk;
}

// ---------------- pre: embedding chain + dual(i=0), BM=16 ----------------
__global__ __launch_bounds__(256) void k_pre(
    const short* __restrict__ wimg, const float* __restrict__ bimg,
    const int* __restrict__ Z, const float* __restrict__ M,
    const float* __restrict__ QaA, const float* __restrict__ QaB,
    const float* __restrict__ em_W0, const float* __restrict__ em_b0,
    float* __restrict__ x, float* __restrict__ xi, float* __restrict__ xj)
{
    __shared__ __align__(16) short As[2048];
    __shared__ __align__(16) short Ts[2048];
    __shared__ float fs[16][4];
    const int tid = threadIdx.x, wv = tid>>6, ln = tid&63, g = ln>>4, l15 = ln&15;
    const int r0 = blockIdx.x*16;
    const int c0 = wv*32 + l15, c1 = c0 + 16;
    bh8 bU[8], bV[8];
    if (tid < 64){
        int rr = tid>>2, k = tid&3;
        int a = r0 + rr;
        fs[rr][k] = (k==0) ? (float)Z[a] : (k==1) ? M[a] : (k==2) ? QaA[a] : QaB[a];
    }
    __syncthreads();
    {   // h1 = ssp(f @ em_W0 + b0) -> As
        int row = tid>>4, cb = tid&15;
        bh8 pk;
        #pragma unroll
        for (int t = 0; t < 8; ++t){
            int c = cb*8 + t;
            float v = sspf(em_b0[c] + fs[row][0]*em_W0[c] + fs[row][1]*em_W0[128+c]
                           + fs[row][2]*em_W0[256+c] + fs[row][3]*em_W0[384+c]);
            pk[t] = (short)f2bf(v);
        }
        *(bh8*)&As[row*128 + ((cb ^ (row&7))*8)] = pk;
    }
    loadB8(wimg + 0*16384, g, l15, wv, bU);
    __syncthreads();
    fx4 acc[2];
    float xr[2][4];
    // P1: em_W1  As->Ts
    ZACC2; gemmB(As, bU, g, l15, acc);
    loadB8(wimg + 1*16384, g, l15, wv, bV);
    epiS_ts(Ts, acc, bimg + 0*128, g, c0, c1);
    __syncthreads();
    // P2: em_W2  Ts -> x, As
    ZACC2; gemmB(Ts, bV, g, l15, acc);
    loadB8(wimg + 2*16384, g, l15, wv, bU);
    {
        const float* b = bimg + 1*128;
        float b0 = b[c0], b1 = b[c1];
        #pragma unroll
        for (int r = 0; r < 4; ++r){
            xr[0][r] = acc[0][r] + b0;
            xr[1][r] = acc[1][r] + b1;
        }
    }
    storeS_xr(x, xr, r0, g, c0, c1);
    writeS_xr(As, xr, g, c0, c1);
    __syncthreads();
    // P3: dual i=0 reads As
    ZACC2; gemmB(As, bU, g, l15, acc);
    loadB8(wimg + 5*16384, g, l15, wv, bV);
    storeS_ssp(xi, acc, bimg + 2*128, r0, g, c0, c1);
    ZACC2; gemmB(As, bV, g, l15, acc);
    storeS_ssp(xj, acc, bimg + 5*128, r0, g, c0, c1);
}

// ---------------- post chain, BM=16 streaming, b-prefetch ping-pong ----------------
__global__ __launch_bounds__(256) void k_post(
    const short* __restrict__ wimg, const float* __restrict__ bimg,
    const float* __restrict__ mb, float* __restrict__ x,
    short* __restrict__ Aimg, float* __restrict__ xi, float* __restrict__ xj,
    int i, int dodual)
{
    __shared__ __align__(16) short As[2048];
    __shared__ __align__(16) short Ts[2048];
    const int tid = threadIdx.x, wv = tid>>6, ln = tid&63, g = ln>>4, l15 = ln&15;
    const int r0 = blockIdx.x*16;
    const int c0 = wv*32 + l15, c1 = c0 + 16;
    bh8 bU[8], bV[8];
    float xr[2][4];
    #pragma unroll
    for (int r = 0; r < 4; ++r){
        size_t row = (size_t)(r0 + g*4 + r);
        xr[0][r] = mb[row*FD + c0];
        xr[1][r] = mb[row*FD + c1];
    }
    stage_A16(As, mb, r0, tid);
    loadB8(wimg + (size_t)(11+2*i)*16384, g, l15, wv, bU);
    __syncthreads();
    fx4 acc[2];
    // P1: irW1[i,0]  As->Ts
    ZACC2; gemmB(As, bU, g, l15, acc);
    loadB8(wimg + (size_t)(17+2*i)*16384, g, l15, wv, bV);
    epiS_ts(Ts, acc, bimg + (11+2*i)*128, g, c0, c1);
    __syncthreads();
    // P2: irW2[i,0]  Ts->As
    ZACC2; gemmB(Ts, bV, g, l15, acc);
    loadB8(wimg + (size_t)(12+2*i)*16384, g, l15, wv, bU);
    epiS_xadd(xr, acc, bimg + (17+2*i)*128, c0, c1);
    writeS_xr(As, xr, g, c0, c1);
    __syncthreads();
    // P3: irW1[i,1]  As->Ts
    ZACC2; gemmB(As, bU, g, l15, acc);
    loadB8(wimg + (size_t)(18+2*i)*16384, g, l15, wv, bV);
    epiS_ts(Ts, acc, bimg + (12+2*i)*128, g, c0, c1);
    __syncthreads();
    // P4: irW2[i,1]  Ts->As
    ZACC2; gemmB(Ts, bV, g, l15, acc);
    loadB8(wimg + (size_t)(8+i)*16384, g, l15, wv, bU);
    epiS_xadd(xr, acc, bimg + (18+2*i)*128, c0, c1);
    writeS_xr(As, xr, g, c0, c1);
    __syncthreads();
    // P5: iWout  As->Ts ; xr = iu*xold + acc + b
    ZACC2; gemmB(As, bU, g, l15, acc);
    loadB8(wimg + (size_t)(23+2*i)*16384, g, l15, wv, bV);
    {
        const float* bb = bimg + (8+i)*128;
        const float* uu = bimg + (41+i)*128;
        float b0 = bb[c0], b1 = bb[c1], u0 = uu[c0], u1 = uu[c1];
        #pragma unroll
        for (int r = 0; r < 4; ++r){
            size_t row = (size_t)(r0 + g*4 + r);
            xr[0][r] = u0*x[row*FD + c0] + acc[0][r] + b0;
            xr[1][r] = u1*x[row*FD + c1] + acc[1][r] + b1;
        }
    }
    writeS_xr(Ts, xr, g, c0, c1);
    __syncthreads();
    // P6: arW1[i,0]  Ts->As
    ZACC2; gemmB(Ts, bV, g, l15, acc);
    loadB8(wimg + (size_t)(29+2*i)*16384, g, l15, wv, bU);
    epiS_ts(As, acc, bimg + (23+2*i)*128, g, c0, c1);
    __syncthreads();
    // P7: arW2[i,0]  As->Ts
    ZACC2; gemmB(As, bU, g, l15, acc);
    loadB8(wimg + (size_t)(24+2*i)*16384, g, l15, wv, bV);
    epiS_xadd(xr, acc, bimg + (29+2*i)*128, c0, c1);
    writeS_xr(Ts, xr, g, c0, c1);
    __syncthreads();
    // P8: arW1[i,1]  Ts->As
    ZACC2; gemmB(Ts, bV, g, l15, acc);
    loadB8(wimg + (size_t)(30+2*i)*16384, g, l15, wv, bU);
    epiS_ts(As, acc, bimg + (24+2*i)*128, g, c0, c1);
    __syncthreads();
    // P9: arW2[i,1]  As-> x, Ts
    ZACC2; gemmB(As, bU, g, l15, acc);
    loadB8(wimg + (size_t)(dodual ? (3+i) : (35+i))*16384, g, l15, wv, bV);
    epiS_xadd(xr, acc, bimg + (30+2*i)*128, c0, c1);
    storeS_xr(x, xr, r0, g, c0, c1);
    writeS_xr(Ts, xr, g, c0, c1);
    __syncthreads();
    // P10: duals + orW1 read Ts
    if (dodual){
        ZACC2; gemmB(Ts, bV, g, l15, acc);
        loadB8(wimg + (size_t)(6+i)*16384, g, l15, wv, bU);
        storeS_ssp(xi, acc, bimg + (3+i)*128, r0, g, c0, c1);
        ZACC2; gemmB(Ts, bU, g, l15, acc);
        loadB8(wimg + (size_t)(35+i)*16384, g, l15, wv, bV);
        storeS_ssp(xj, acc, bimg + (6+i)*128, r0, g, c0, c1);
        ZACC2; gemmB(Ts, bV, g, l15, acc);
        loadB8(wimg + (size_t)(38+i)*16384, g, l15, wv, bU);
        epiS_ts(As, acc, bimg + (35+i)*128, g, c0, c1);
    } else {
        ZACC2; gemmB(Ts, bV, g, l15, acc);
        loadB8(wimg + (size_t)(38+i)*16384, g, l15, wv, bU);
        epiS_ts(As, acc, bimg + (35+i)*128, g, c0, c1);
    }
    __syncthreads();
    // P11: orW2  As-> Aimg segment i (bf16 ssp image, K-offset i*128)
    ZACC2; gemmB(As, bU, g, l15, acc);
    {
        const float* bb = bimg + (38+i)*128;
        float b0 = bb[c0], b1 = bb[c1];
        #pragma unroll
        for (int r = 0; r < 4; ++r){
            int row = r0 + g*4 + r;
            float v0 = xr[0][r] + acc[0][r] + b0;
            float v1 = xr[1][r] + acc[1][r] + b1;
            int k0 = i*128 + c0, k1 = i*128 + c1;
            Aimg[(size_t)row*384 + (((k0>>3) ^ (row&7))*8) + (k0&7)] = (short)f2bf(sspf(v0));
            Aimg[(size_t)row*384 + (((k1>>3) ^ (row&7))*8) + (k1&7)] = (short)f2bf(sspf(v1));
        }
    }
}

// ---------------- message aggregation: rbf computed in-kernel ----------------
__global__ __launch_bounds__(256) void k_agg_mfma(
    const float* __restrict__ dij, const short* __restrict__ wri,
    const int* __restrict__ idxj, const float* __restrict__ xi,
    const float* __restrict__ xj, float* __restrict__ mout,
    float gamma, float mu0, float dmu)
{
    __shared__ short Rb[256*64];   // 32 KB
    __shared__ short Wr[128*64];   // 16 KB
    __shared__ int Jd[256];
    const int tid = threadIdx.x;
    const int wv = tid >> 6, ln = tid & 63;
    const int e0 = blockIdx.x * 256;
    {
        const char* g2 = (const char*)wri;
        char* l2 = (char*)Wr;
        #pragma unroll
        for (int i = 0; i < 4; ++i){
            int off = wv*4096 + i*1024;
            gll16(g2 + off + ln*16, l2 + off);
        }
        Jd[tid] = idxj[e0 + tid];
    }
    {   // compute rbf row for edge e0+tid directly into Rb (swizzled)
        float d = dij[e0 + tid];
        float t = d * 0.1f;
        float cut = 0.0f;
        if (d < 10.0f){
            float t2 = t*t, t3 = t2*t, t4 = t2*t2, t5 = t4*t;
            cut = 1.0f - 6.0f*t5 + 15.0f*t4 - 10.0f*t3;
        }
        float ed = __expf(-d);
        int row = tid;
        #pragma unroll
        for (int s = 0; s < 8; ++s){
            bh8 pk;
            #pragma unroll
            for (int jj = 0; jj < 8; ++jj){
                float u = ed - (mu0 + (float)(s*8+jj)*dmu);
                pk[jj] = (short)f2bf(cut * __expf(-gamma*u*u));
            }
            *(bh8*)&Rb[row*64 + ((s ^ (row&7))*8)] = pk;
        }
    }
    __syncthreads();
    const int g = ln >> 4, l15 = ln & 15;
    bh8 a[4][2];
    #pragma unroll
    for (int mt = 0; mt < 4; ++mt){
        int el = wv*64 + mt*16 + l15;
        #pragma unroll
        for (int kk = 0; kk < 2; ++kk)
            a[mt][kk] = *(const bh8*)&Rb[el*64 + (((kk*4+g) ^ (el&7))*8)];
    }
    float pa[2][8];
    #pragma unroll
    for (int q = 0; q < 8; ++q){ pa[0][q]=0.f; pa[1][q]=0.f; }
    #pragma unroll
    for (int h = 0; h < 2; ++h){
        fx4 acc[4][4];
        #pragma unroll
        for (int mt = 0; mt < 4; ++mt)
            #pragma unroll
            for (int nt = 0; nt < 4; ++nt) acc[mt][nt] = (fx4){0,0,0,0};
        #pragma unroll
        for (int kk = 0; kk < 2; ++kk){
            #pragma unroll
            for (int nt = 0; nt < 4; ++nt){
                int n = h*64 + nt*16 + l15;
                bh8 b = *(const bh8*)&Wr[n*64 + (((kk*4+g) ^ (n&7))*8)];
                #pragma unroll
                for (int mt = 0; mt < 4; ++mt)
                    acc[mt][nt] = mfma16(a[mt][kk], b, acc[mt][nt]);
            }
        }
        #pragma unroll
        for (int mt = 0; mt < 4; ++mt){
            int at = mt >> 1;
            int jv[4];
            #pragma unroll
            for (int r = 0; r < 4; ++r) jv[r] = Jd[wv*64 + mt*16 + g*4 + r];
            #pragma unroll
            for (int nt = 0; nt < 4; ++nt){
                int col = h*64 + nt*16 + l15;
                float s = 0.f;
                #pragma unroll
                for (int r = 0; r < 4; ++r)
                    s += acc[mt][nt][r] * xj[(size_t)jv[r]*FD + col];
                pa[at][h*4+nt] += s;
            }
        }
    }
    #pragma unroll
    for (int at = 0; at < 2; ++at)
        #pragma unroll
        for (int q = 0; q < 8; ++q){
            float v = pa[at][q];
            v += __shfl_xor(v, 16);
            v += __shfl_xor(v, 32);
            pa[at][q] = v;
        }
    if (g == 0){
        #pragma unroll
        for (int at = 0; at < 2; ++at){
            int ga = blockIdx.x*8 + wv*2 + at;
            #pragma unroll
            for (int q = 0; q < 8; ++q){
                int col = (q>>2)*64 + (q&3)*16 + l15;
                mout[(size_t)ga*FD + col] = xi[(size_t)ga*FD + col] + pa[at][q];
            }
        }
    }
}

// ---------------- j=0: out4 from Aimg (all three segments) ----------------
__global__ void k_out4all(const short* __restrict__ Aimg, const float* __restrict__ oW,
                          float* __restrict__ out4){
    int gid = blockIdx.x*256 + threadIdx.x;
    int a = gid >> 6;
    int lane = threadIdx.x & 63;
    if (a >= NA) return;
    float p0=0.f, p1=0.f, p2=0.f, p3=0.f;
    #pragma unroll
    for (int seg = 0; seg < 3; ++seg){
        const float* oWs = oW + (size_t)seg*FD*NOUTS_C;
        int k0 = seg*128 + lane, k1 = k0 + 64;
        float y0 = bf2f((unsigned short)Aimg[(size_t)a*384 + (((k0>>3) ^ (a&7))*8) + (k0&7)]);
        float y1 = bf2f((unsigned short)Aimg[(size_t)a*384 + (((k1>>3) ^ (a&7))*8) + (k1&7)]);
        const float* w0 = oWs + (size_t)lane*NOUTS_C;
        const float* w1 = oWs + (size_t)(lane+64)*NOUTS_C;
        p0 += y0*w0[0] + y1*w1[0];
        p1 += y0*w0[1] + y1*w1[1];
        p2 += y0*w0[2] + y1*w1[2];
        p3 += y0*w0[3] + y1*w1[3];
    }
    #pragma unroll
    for (int off = 32; off > 0; off >>= 1){
        p0 += __shfl_down(p0, off);
        p1 += __shfl_down(p1, off);
        p2 += __shfl_down(p2, off);
        p3 += __shfl_down(p3, off);
    }
    if (lane == 0){
        out4[a*4+0] = p0; out4[a*4+1] = p1;
        out4[a*4+2] = p2; out4[a*4+3] = p3;
    }
}

// ---------------- charge equilibration ----------------
__global__ void k_molsum(const float* __restrict__ out4, const int* __restrict__ mol,
                         float* __restrict__ sums){
    int a = blockIdx.x*256 + threadIdx.x;
    if (a >= NA) return;
    int m = mol[a];
    atomicAdd(&sums[m],     out4[a*4+0]);
    atomicAdd(&sums[64+m],  out4[a*4+1]);
    atomicAdd(&sums[128+m], out4[a*4+2]);
    atomicAdd(&sums[192+m], out4[a*4+3]);
}

__global__ void k_qaupd(const float* __restrict__ out4, const int* __restrict__ mol,
                        const float* __restrict__ sums, const float* __restrict__ QAmol,
                        const float* __restrict__ QBmol, float* __restrict__ QaA,
                        float* __restrict__ QaB){
    int a = blockIdx.x*256 + threadIdx.x;
    if (a >= NA) return;
    int m = mol[a];
    float qa_n = out4[a*4+0], fa = out4[a*4+1];
    float qb_n = out4[a*4+2], fb = out4[a*4+3];
    QaA[a] = qa_n + fa * ((QAmol[m] - sums[m])     / sums[64+m]);
    QaB[a] = qb_n + fb * ((QBmol[m] - sums[128+m]) / sums[192+m]);
}

// ---------------- final head: A in LDS (48 KB), B streamed frag-linear ----------------
// grid (157 rowblocks, 16 colgroups)
__global__ __launch_bounds__(256) void k_final3(
    const short* __restrict__ Aimg, const short* __restrict__ oWfrag,
    float* __restrict__ outp, float* __restrict__ nh_acc)
{
    __shared__ __align__(16) short As[64*384];     // 48 KB
    const int tid = threadIdx.x, wv = tid>>6, ln = tid&63, g = ln>>4, l15 = ln&15;
    const int a0 = blockIdx.x * 64;
    const int cg = blockIdx.y;
    {
        const char* gA = (const char*)(Aimg + (size_t)a0*384);
        char* lA = (char*)As;
        #pragma unroll
        for (int i = 0; i < 12; ++i){
            int off = wv*12288 + i*1024;
            gll16(gA + off + ln*16, lA + off);
        }
    }
    __syncthreads();
    const bh8* Bf = (const bh8*)oWfrag + (size_t)cg*12*8*64;
    const int arow = wv*16 + l15;
    fx4 osum[8], p2[8];
    #pragma unroll
    for (int nt = 0; nt < 8; ++nt){ osum[nt] = (fx4){0,0,0,0}; p2[nt] = (fx4){0,0,0,0}; }
    float nh = 0.f;
    for (int seg = 0; seg < 3; ++seg){
        fx4 acc[8];
        #pragma unroll
        for (int nt = 0; nt < 8; ++nt) acc[nt] = (fx4){0,0,0,0};
        #pragma unroll
        for (int kkl = 0; kkl < 4; ++kkl){
            int kk2 = seg*4 + kkl;
            bh8 b[8];
            #pragma unroll
            for (int nt = 0; nt < 8; ++nt)
                b[nt] = Bf[((size_t)kk2*8 + nt)*64 + g*16 + l15];
            int s = kk2*4 + g;
            bh8 a = *(const bh8*)&As[arow*384 + ((s ^ (arow&7))*8)];
            #pragma unroll
            for (int nt = 0; nt < 8; ++nt)
                acc[nt] = mfma16(a, b[nt], acc[nt]);
        }
        #pragma unroll
        for (int nt = 0; nt < 8; ++nt)
        #pragma unroll
        for (int r = 0; r < 4; ++r){
            float o = acc[nt][r];
            osum[nt][r] += o;
            if (seg > 0){
                int A = a0 + wv*16 + g*4 + r;
                int col = cg*128 + nt*16 + l15;
                if (A >= 4 && A < NA && col < NOUTS_C){
                    float o2 = o*o;
                    float den = o2 + p2[nt][r] + 1e-7f;
                    float rr;
                    asm("v_rcp_f32 %0, %1" : "=v"(rr) : "v"(den));
                    nh += o2 * rr;
                }
            }
            p2[nt][r] = o*o;
        }
    }
    #pragma unroll
    for (int nt = 0; nt < 8; ++nt){
        int col = cg*128 + nt*16 + l15;
        #pragma unroll
        for (int r = 0; r < 4; ++r){
            int A = a0 + wv*16 + g*4 + r;
            if (A < NA && col >= 4 && col < NOUTS_C){
                float v = osum[nt][r];
                if (col > 4) v = fmaxf(v, 0.f);
                outp[(size_t)A*NOUT_FINAL + (col - 4)] = v;
            }
        }
    }
    #pragma unroll
    for (int off = 32; off > 0; off >>= 1) nh += __shfl_down(nh, off);
    if (ln == 0) atomicAdd(nh_acc, nh);
}

__global__ void k_finalize(const float* __restrict__ nh_acc, float* __restrict__ nh_out){
    *nh_out = *nh_acc * (1.0f / (float)((NA - 4) * NOUTS_C));
}

// =====================================================================
extern "C" void kernel_launch(void* const* d_in, const int* in_sizes, int n_in,
                              void* d_out, int out_size, void* d_ws, size_t ws_size,
                              hipStream_t stream)
{
    const float* R       = (const float*)d_in[0];
    const float* M       = (const float*)d_in[1];
    const float* QaAlpha = (const float*)d_in[2];
    const float* QaBeta  = (const float*)d_in[3];
    const float* em_W0   = (const float*)d_in[4];
    const float* em_b0   = (const float*)d_in[5];
    const float* em_W1   = (const float*)d_in[6];
    const float* em_b1   = (const float*)d_in[7];
    const float* em_W2   = (const float*)d_in[8];
    const float* em_b2   = (const float*)d_in[9];
    const float* iWrbf   = (const float*)d_in[10];
    const float* iWi     = (const float*)d_in[11];
    const float* ibi     = (const float*)d_in[12];
    const float* iWj     = (const float*)d_in[13];
    const float* ibj     = (const float*)d_in[14];
    const float* irW1    = (const float*)d_in[15];
    const float* irb1    = (const float*)d_in[16];
    const float* irW2    = (const float*)d_in[17];
    const float* irb2    = (const float*)d_in[18];
    const float* iWout   = (const float*)d_in[19];
    const float* ibout   = (const float*)d_in[20];
    const float* iu      = (const float*)d_in[21];
    const float* arW1    = (const float*)d_in[22];
    const float* arb1    = (const float*)d_in[23];
    const float* arW2    = (const float*)d_in[24];
    const float* arb2    = (const float*)d_in[25];
    const float* orW1    = (const float*)d_in[26];
    const float* orb1    = (const float*)d_in[27];
    const float* orW2    = (const float*)d_in[28];
    const float* orb2    = (const float*)d_in[29];
    const float* oW      = (const float*)d_in[30];
    const int*   Z       = (const int*)d_in[31];
    const int*   idx_i   = (const int*)d_in[32];
    const int*   idx_j   = (const int*)d_in[33];
    const int*   mol     = (const int*)d_in[34];

    float* out    = (float*)d_out;
    float* dij    = out + (size_t)NA*NOUT_FINAL;
    float* nh_out = dij + NE;

    float* fbase = (float*)d_ws;
    size_t fo = 0;
    float* x    = fbase + fo; fo += (size_t)NA*FD;
    float* xi   = fbase + fo; fo += (size_t)NA*FD;
    float* xj   = fbase + fo; fo += (size_t)NA*FD;
    float* mb   = fbase + fo; fo += (size_t)NA*FD;
    float* out4 = fbase + fo; fo += (size_t)NA*4;
    float* sums = fbase + fo; fo += 256;            // zero region start
    float* QAmol= fbase + fo; fo += 64;
    float* QBmol= fbase + fo; fo += 64;
    float* nhac = fbase + fo; fo += 1;              // zero region end
    float* QaA  = fbase + fo; fo += NA;
    float* QaB  = fbase + fo; fo += NA;
    float* bimg = fbase + fo; fo += 44*128;
    size_t sboff = ((fo*4 + 63) / 64) * 64;
    short* sbase = (short*)((char*)d_ws + sboff);
    size_t so = 0;
    short* wimg   = sbase + so; so += (size_t)41*16384;
    short* wrbf   = sbase + so; so += (size_t)3*8192;
    short* oWfrag = sbase + so; so += (size_t)98304*8;
    short* Aimg   = sbase + so; so += (size_t)10048*384;

    hipMemsetAsync(sums, 0, (size_t)(256 + 64 + 64 + 1)*sizeof(float), stream);
    // zero Aimg pad rows (10000..10047) once
    hipMemsetAsync(Aimg + (size_t)10000*384, 0, (size_t)48*384*sizeof(short), stream);

    k_cvtW<<<(41*2048+255)/256, 256, 0, stream>>>(em_W1, em_W2, iWi, iWj, iWout,
                                                  irW1, irW2, arW1, arW2, orW1, orW2, wimg);
    k_cvtB<<<(44*128+255)/256, 256, 0, stream>>>(em_b1, em_b2, ibi, ibj, ibout,
                                                 irb1, irb2, arb1, arb2, orb1, orb2, iu, bimg);
    k_cvt_wrbf<<<(3*1024+255)/256, 256, 0, stream>>>(iWrbf, wrbf);
    k_cvt_oW<<<(98304+255)/256, 256, 0, stream>>>(oW, oWfrag);

    k_dij<<<(NE+255)/256, 256, 0, stream>>>(R, idx_i, idx_j, dij);
    k_init<<<(NA+255)/256, 256, 0, stream>>>(QaAlpha, QaBeta, mol, QaA, QaB, QAmol, QBmol);

    double expn = exp(-10.0);
    float gamma = (float)pow(64.0/(2.0*(1.0-expn)), 2.0);
    float mu0 = (float)expn;
    float dmu = (float)((1.0-expn)/63.0);

    for (int j = 0; j <= 1; ++j){
        k_pre<<<625, 256, 0, stream>>>(wimg, bimg, Z, M, QaA, QaB, em_W0, em_b0, x, xi, xj);
        for (int i = 0; i < 3; ++i){
            k_agg_mfma<<<1250, 256, 0, stream>>>(dij, wrbf + (size_t)i*8192, idx_j, xi, xj, mb,
                                                 gamma, mu0, dmu);
            k_post<<<625, 256, 0, stream>>>(wimg, bimg, mb, x, Aimg, xi, xj, i, (i<2) ? 1 : 0);
        }
        if (j == 0){
            k_out4all<<<(NA*64)/256, 256, 0, stream>>>(Aimg, oW, out4);
            k_molsum<<<(NA+255)/256, 256, 0, stream>>>(out4, mol, sums);
            k_qaupd<<<(NA+255)/256, 256, 0, stream>>>(out4, mol, sums, QAmol, QBmol, QaA, QaB);
        }
    }
    k_final3<<<dim3(157,16), 256, 0, stream>>>(Aimg, oWfrag, out, nhac);
    k_finalize<<<1, 1, 0, stream>>>(nhac, nh_out);
}